// Round 2
// baseline (185.260 us; speedup 1.0000x reference)
//
#include <hip/hip_runtime.h>
#include <hip/hip_bf16.h>
#include <stdint.h>

typedef float  f32x4 __attribute__((ext_vector_type(4)));
typedef short  s16x8 __attribute__((ext_vector_type(8)));
typedef short  s16x4 __attribute__((ext_vector_type(4)));
typedef int    i32x4 __attribute__((ext_vector_type(4)));

#define DI __device__ __forceinline__

constexpr int Bb = 2, Tt = 2048, Ff = 1024, Hh = 16, Dk = 64;
constexpr int Mm = Bb * Tt;  // 4096 rows
constexpr float LOG2E = 1.44269504088896340736f;

DI ushort f2bf(float f) {  // round-to-nearest-even f32 -> bf16 (raw bits)
  unsigned u = __float_as_uint(f);
  unsigned r = (u + 0x7fffu + ((u >> 16) & 1u)) >> 16;
  return (ushort)r;
}

DI int cvt_pk_bf16(float lo, float hi) {  // packed f32x2 -> bf16x2 (v_cvt_pk_bf16_f32)
  __hip_bfloat162 t = __float22bfloat162_rn(make_float2(lo, hi));
  int w;
  __builtin_memcpy(&w, &t, 4);
  return w;
}

DI void gload16(const void* g, void* l) {  // async global->LDS, 16B/lane, dst = wave-uniform base + lane*16
  __builtin_amdgcn_global_load_lds(
      (__attribute__((address_space(1))) void*)g,
      (__attribute__((address_space(3))) void*)l, 16, 0, 0);
}

// ---------------- f32 -> bf16 convert, 3 tensors in one launch ----------------
__global__ __launch_bounds__(256) void cvt3_kernel(const float* __restrict__ s0, const float* __restrict__ s1,
                                                   const float* __restrict__ s2, ushort* __restrict__ d0,
                                                   ushort* __restrict__ d1, ushort* __restrict__ d2, int n8) {
  const float* src = blockIdx.y == 0 ? s0 : (blockIdx.y == 1 ? s1 : s2);
  ushort* dst = blockIdx.y == 0 ? d0 : (blockIdx.y == 1 ? d1 : d2);
  int i = blockIdx.x * 256 + threadIdx.x;
  if (i >= n8) return;
  const float4* s4 = (const float4*)src + (size_t)i * 2;
  float4 a = s4[0], b = s4[1];
  s16x8 o;
  o[0] = (short)f2bf(a.x); o[1] = (short)f2bf(a.y); o[2] = (short)f2bf(a.z); o[3] = (short)f2bf(a.w);
  o[4] = (short)f2bf(b.x); o[5] = (short)f2bf(b.y); o[6] = (short)f2bf(b.z); o[7] = (short)f2bf(b.w);
  *((s16x8*)dst + i) = o;
}

// ---------------- weight transpose+convert: W[k][n] f32 -> Wt[n][k] bf16 ----------------
__global__ __launch_bounds__(256) void wtrans_kernel(const float* __restrict__ W0, const float* __restrict__ W1,
                                                     const float* __restrict__ W2, const float* __restrict__ W3,
                                                     ushort* __restrict__ Wt0, ushort* __restrict__ Wt1,
                                                     ushort* __restrict__ Wt2, ushort* __restrict__ Wt3) {
  const float* W; ushort* Wt;
  switch (blockIdx.z) {
    case 0: W = W0; Wt = Wt0; break;
    case 1: W = W1; Wt = Wt1; break;
    case 2: W = W2; Wt = Wt2; break;
    default: W = W3; Wt = Wt3; break;
  }
  __shared__ float tile[64][65];
  int k0 = blockIdx.y * 64, n0 = blockIdx.x * 64;
  int t = threadIdx.x, r = t >> 4, c4 = (t & 15) * 4;
#pragma unroll
  for (int i = 0; i < 4; i++) {
    int row = r + i * 16;
    const float4 v = *(const float4*)(W + (size_t)(k0 + row) * Ff + n0 + c4);
    tile[row][c4] = v.x; tile[row][c4 + 1] = v.y; tile[row][c4 + 2] = v.z; tile[row][c4 + 3] = v.w;
  }
  __syncthreads();
#pragma unroll
  for (int i = 0; i < 4; i++) {
    int n = r + i * 16;
    s16x4 o;
#pragma unroll
    for (int j = 0; j < 4; j++) o[j] = (short)f2bf(tile[c4 + j][n]);
    *(s16x4*)(Wt + (size_t)(n0 + n) * Ff + k0 + c4) = o;
  }
}

// ---------------- mask tile summary: flag=1 iff whole 64x64 tile > 0 ----------------
__global__ __launch_bounds__(256) void maskflag_kernel(const int* __restrict__ mask, int* __restrict__ flags) {
  int kb = blockIdx.x, qb = blockIdx.y, b = blockIdx.z;
  int t = threadIdx.x;
  __shared__ int s;
  if (t == 0) s = 1;
  __syncthreads();
  int ok = 1;
#pragma unroll
  for (int i = 0; i < 4; i++) {
    int row = qb * 64 + (t >> 4) + i * 16;
    const int4 v = *(const int4*)(mask + ((size_t)b * Tt + row) * Tt + kb * 64 + (t & 15) * 4);
    ok &= (v.x > 0) & (v.y > 0) & (v.z > 0) & (v.w > 0);
  }
  atomicAnd(&s, ok);
  __syncthreads();
  if (t == 0) flags[(b * 32 + qb) * 32 + kb] = s;
}

// ---------------- bf16 GEMM, C = A[M,K] * Bt[N,K]^T (+bias)*scale ----------------
// A staged through XOR-swizzled double-buffered LDS (1 barrier/K-step);
// B (weights, 2MB, L2-resident) read as fragments DIRECT from global — no B LDS traffic.
// mode 0: f32 row-major out. mode 1: bf16 row-major out. mode 2: bf16 V-fragment layout
//   (Vpt[(b*Ff+n)][kv], columns pi-permuted per 64-block: kv=32c+16f+4g+r stored at p=32c+8g+4f+r).
DI void gemm_core(const ushort* __restrict__ A, const ushort* __restrict__ Bt,
                  const float* __restrict__ bias, void* __restrict__ Cout, float scale, int mode,
                  int m0, int n0) {
  __shared__ ushort Ads[2][128 * 64];  // 32 KB total (A only, double-buffered)
  const int tid = threadIdx.x, lane = tid & 63, w = tid >> 6;
  const int wr = w >> 1, wc = w & 1;
  const int g = lane >> 4, ln = lane & 15;
  const int srow = lane >> 3;
  const int swzch = ((lane & 7) ^ srow) * 8;  // inverse-swizzled source chunk (ushorts)

  f32x4 acc[4][4];
#pragma unroll
  for (int m = 0; m < 4; m++)
#pragma unroll
    for (int n = 0; n < 4; n++) acc[m][n] = (f32x4){0.f, 0.f, 0.f, 0.f};

  // prologue: stage A K-tile 0 (pre-swizzled source, linear LDS dst)
#pragma unroll
  for (int it = 0; it < 4; ++it) {
    const int row = w * 32 + it * 8;
    gload16(A + (size_t)(m0 + row + srow) * Ff + swzch, Ads[0] + row * 64);
  }
  __syncthreads();

  const ushort* Brow = Bt + (size_t)(n0 + wc * 64 + ln) * Ff;  // this lane's B base row

  for (int kk = 0; kk < 16; ++kk) {
    const int cur = kk & 1;
    const int k0 = kk * 64;
    // prefetch next A K-tile into the other buffer (overlaps compute below)
    if (kk < 15) {
#pragma unroll
      for (int it = 0; it < 4; ++it) {
        const int row = w * 32 + it * 8;
        gload16(A + (size_t)(m0 + row + srow) * Ff + k0 + 64 + swzch, Ads[cur ^ 1] + row * 64);
      }
    }
    // B fragments direct from global (hot in L2): identical bytes to the old LDS-staged reads
    s16x8 bf[4][2];
#pragma unroll
    for (int n = 0; n < 4; n++)
#pragma unroll
      for (int c = 0; c < 2; c++)
        bf[n][c] = *(const s16x8*)(Brow + (size_t)n * 16 * Ff + k0 + c * 32 + g * 8);
    // A fragments from swizzled LDS (conflict-free)
    s16x8 af[4][2];
#pragma unroll
    for (int m = 0; m < 4; m++)
#pragma unroll
      for (int c = 0; c < 2; c++) {
        const int ra = wr * 64 + m * 16 + ln;
        const int off = (c * 64 + g * 16) ^ ((ra & 7) << 4);
        af[m][c] = *(const s16x8*)((const char*)(Ads[cur]) + ra * 128 + off);
      }
#pragma unroll
    for (int m = 0; m < 4; m++)
#pragma unroll
      for (int n = 0; n < 4; n++)
#pragma unroll
        for (int c = 0; c < 2; c++)
          acc[m][n] = __builtin_amdgcn_mfma_f32_16x16x32_bf16(af[m][c], bf[n][c], acc[m][n], 0, 0, 0);
    if (kk < 15) __syncthreads();  // drains prefetch vmcnt + protects buffer swap
  }
#pragma unroll
  for (int m = 0; m < 4; m++) {
    const int r0 = m0 + wr * 64 + m * 16 + g * 4;
#pragma unroll
    for (int n = 0; n < 4; n++) {
      const int col = n0 + wc * 64 + n * 16 + ln;
      const float bv = bias[col];
      if (mode == 2) {
        // V-fragment store: batch bb, row-in-batch rb, pi^-1 on kv within 64-block
        const int bb = r0 >> 11, rb = r0 & 2047;
        const int x = rb & 63;
        const int pbase = (x & 0x20) | ((x & 0x0C) << 1) | ((x & 0x10) >> 2);
        s16x4 o4;
#pragma unroll
        for (int r = 0; r < 4; r++) o4[r] = (short)f2bf(acc[m][n][r] + bv);
        *(s16x4*)((ushort*)Cout + ((size_t)bb * Ff + col) * Tt + (rb & ~63) + pbase) = o4;
      } else {
#pragma unroll
        for (int r = 0; r < 4; r++) {
          const float val = (acc[m][n][r] + bv) * scale;
          if (mode == 1)
            ((ushort*)Cout)[(size_t)(r0 + r) * Ff + col] = f2bf(val);
          else
            ((float*)Cout)[(size_t)(r0 + r) * Ff + col] = val;
        }
      }
    }
  }
}

__global__ __launch_bounds__(256) void qkv_gemm_kernel(
    const ushort* __restrict__ Xq, const ushort* __restrict__ Xk, const ushort* __restrict__ Xv,
    const ushort* __restrict__ Wqt, const ushort* __restrict__ Wkt, const ushort* __restrict__ Wvt,
    const float* __restrict__ bq, const float* __restrict__ bk, const float* __restrict__ bv,
    ushort* __restrict__ Qb, ushort* __restrict__ Kb, ushort* __restrict__ Vpt) {
  // T1: XCD-chunked bijective block swizzle (768 blocks -> 96 contiguous per XCD)
  const int lin = blockIdx.x + 8 * blockIdx.y + 256 * blockIdx.z;
  const int work = (lin & 7) * 96 + (lin >> 3);
  const int z = work >> 8;
  const int r = work & 255;
  const int m0 = (r >> 3) * 128, n0 = (r & 7) * 128;
  const ushort* A = z == 0 ? Xq : (z == 1 ? Xk : Xv);
  const ushort* Wt = z == 0 ? Wqt : (z == 1 ? Wkt : Wvt);
  const float* bias = z == 0 ? bq : (z == 1 ? bk : bv);
  void* C = z == 0 ? (void*)Qb : (z == 1 ? (void*)Kb : (void*)Vpt);
  // z==0: fold 1/sqrt(64) AND log2(e) into Q so softmax runs in exp2 domain
  const float scale = z == 0 ? 0.125f * LOG2E : 1.0f;
  gemm_core(A, Wt, bias, C, scale, z == 2 ? 2 : 1, m0, n0);
}

__global__ __launch_bounds__(256) void out_gemm_kernel(const ushort* __restrict__ AO,
                                                       const ushort* __restrict__ Wot,
                                                       const float* __restrict__ bo,
                                                       float* __restrict__ Out) {
  // T1: XCD-chunked bijective block swizzle (256 blocks -> 32 contiguous per XCD)
  const int lin = blockIdx.x + 8 * blockIdx.y;
  const int work = (lin & 7) * 32 + (lin >> 3);
  const int m0 = (work >> 3) * 128, n0 = (work & 7) * 128;
  gemm_core(AO, Wot, bo, Out, 1.0f, 0, m0, n0);
}

// ---------------- flash attention (max-free exp2-domain softmax) ----------------
// grid (qb=32, h=16, b=2), 256 thr (4 waves). BQ=64 (16 q-rows/wave), BK=64, D=64.
// S'^T = mfma(K_frag, Q_frag), scores already in log2 domain (Q pre-scaled by 0.125*log2e).
// Score magnitudes are bounded (|s_log2| << 127) so p = exp2(s) RAW is exact softmax up to a
// global 2^m factor that cancels in o/l: no max tracking, no rescale, no in-loop shuffles.
// lane (g,ln): q = w*16+ln, kv(sf[ks][r]) = kt*64 + 16ks + 4g + r.
// PV sigma k-slots on BOTH operands: slot (c,g,i=4f+r) <-> kv = 32c+16f+4g+r;
//   A-op packed in-register via v_cvt_pk; B-op = single b128 from pi-ordered d-major V LDS.
__global__ __launch_bounds__(256) void flash_kernel(
    const ushort* __restrict__ Qb, const ushort* __restrict__ Kb, const ushort* __restrict__ Vpt,
    const int* __restrict__ flags, const int* __restrict__ mask, ushort* __restrict__ AO) {
  __shared__ ushort Ks[2][64 * 64];
  __shared__ ushort Vs[2][64 * 64];
  // T1: XCD-chunked bijective block swizzle (1024 blocks -> 128 per XCD = 4 heads' KV, L2-fit)
  const int lin = blockIdx.x + 32 * (blockIdx.y + 16 * blockIdx.z);
  const int work = (lin & 7) * 128 + (lin >> 3);
  const int qb = work & 31, h = (work >> 5) & 15, b = work >> 9;
  const int tid = threadIdx.x, lane = tid & 63, w = tid >> 6;
  const int g = lane >> 4, ln = lane & 15;

  const ushort* Qg = Qb + ((size_t)b * Tt + qb * 64) * Ff + h * Dk;
  const ushort* Kg = Kb + ((size_t)b * Tt) * Ff + h * Dk;
  const ushort* Vg = Vpt + (size_t)(b * Ff + h * Dk) * Tt;  // rows d, stride Tt, cols pi-ordered

  const int srow = lane >> 3;
  const int swzch = ((lane & 7) ^ srow) * 8;  // inverse-swizzled source chunk (ushorts)

  // prologue: stage tile 0 (K,V)
#pragma unroll
  for (int it = 0; it < 2; ++it) {
    const int row = w * 16 + it * 8;
    gload16(Kg + (size_t)(row + srow) * Ff + swzch, Ks[0] + row * 64);
    gload16(Vg + (size_t)(row + srow) * Tt + swzch, Vs[0] + row * 64);
  }
  // preload mask-tile bitmask (bit kt set => tile needs masking)
  const int* flagrow = flags + (b * 32 + qb) * 32;
  const int myflag = (lane < 32) ? flagrow[lane] : 1;

  // Q fragments DIRECT from global (one-time read, no LDS round-trip):
  // qf[c] = Q[q=w*16+ln][d = c*32+g*8 ..+7]
  s16x8 qf[2];
  {
    const ushort* Qrow = Qg + (size_t)(w * 16 + ln) * Ff;
    qf[0] = *(const s16x8*)(Qrow + g * 8);
    qf[1] = *(const s16x8*)(Qrow + 32 + g * 8);
  }
  __syncthreads();
  const unsigned long long bm = __ballot(myflag == 0);

  float l_lane = 0.f;  // lane-local partial softmax denominator (this lane's kv slots for q=w*16+ln)
  f32x4 o[4];
#pragma unroll
  for (int ds = 0; ds < 4; ds++) o[ds] = (f32x4){0.f, 0.f, 0.f, 0.f};

  auto body = [&](const ushort* Kc, const ushort* Vc, ushort* Kn, ushort* Vn, int kt) {
    // --- prefetch tile kt+1 into next buffers (overlaps with compute below) ---
    if (kt + 1 < 32) {
      const ushort* Kg2 = Kg + (size_t)(kt + 1) * 64 * Ff;
      const ushort* Vg2 = Vg + (size_t)(kt + 1) * 64;
#pragma unroll
      for (int it = 0; it < 2; ++it) {
        const int row = w * 16 + it * 8;
        gload16(Kg2 + (size_t)(row + srow) * Ff + swzch, Kn + row * 64);
        gload16(Vg2 + (size_t)(row + srow) * Tt + swzch, Vn + row * 64);
      }
    }
    // --- S'^T = K * Q^T (log2 domain) ---
    f32x4 sf[4];
    __builtin_amdgcn_s_setprio(1);
#pragma unroll
    for (int ks = 0; ks < 4; ++ks) {
      f32x4 a = (f32x4){0.f, 0.f, 0.f, 0.f};
#pragma unroll
      for (int c = 0; c < 2; c++) {
        const int row = ks * 16 + ln;
        const int off = (c * 64 + g * 16) ^ ((row & 7) << 4);
        const s16x8 kf = *(const s16x8*)((const char*)Kc + row * 128 + off);
        a = __builtin_amdgcn_mfma_f32_16x16x32_bf16(kf, qf[c], a, 0, 0, 0);
      }
      sf[ks] = a;
    }
    __builtin_amdgcn_s_setprio(0);
    // --- mask (skipped for all-positive tiles); masked scores -> -10000 -> exp2 -> 0 ---
    if ((bm >> kt) & 1ull) {
      const int qg_ = qb * 64 + w * 16 + ln;
#pragma unroll
      for (int ks = 0; ks < 4; ++ks) {
        const int4 mv = *(const int4*)(mask + ((size_t)b * Tt + qg_) * Tt + kt * 64 + ks * 16 + g * 4);
        if (mv.x <= 0) sf[ks][0] = -10000.f;
        if (mv.y <= 0) sf[ks][1] = -10000.f;
        if (mv.z <= 0) sf[ks][2] = -10000.f;
        if (mv.w <= 0) sf[ks][3] = -10000.f;
      }
    }
    // --- raw exp2 (no max subtraction) + lane-local denominator partials ---
    float s0 = 0.f, s1 = 0.f;
#pragma unroll
    for (int ks = 0; ks < 4; ++ks) {
#pragma unroll
      for (int r = 0; r < 2; ++r) {
        const float p0 = __builtin_amdgcn_exp2f(sf[ks][2 * r]);
        const float p1 = __builtin_amdgcn_exp2f(sf[ks][2 * r + 1]);
        sf[ks][2 * r] = p0; sf[ks][2 * r + 1] = p1;
        s0 += p0; s1 += p1;
      }
    }
    l_lane += s0 + s1;
    // --- pack P A-frags via v_cvt_pk: word w of pa[c] = slots (2w,2w+1), i=4f+r ---
    i32x4 paw[2];
#pragma unroll
    for (int c = 0; c < 2; c++)
#pragma unroll
      for (int f = 0; f < 2; f++)
#pragma unroll
        for (int hh = 0; hh < 2; hh++)
          paw[c][f * 2 + hh] = cvt_pk_bf16(sf[2 * c + f][2 * hh], sf[2 * c + f][2 * hh + 1]);
    const s16x8 pa0 = __builtin_bit_cast(s16x8, paw[0]);
    const s16x8 pa1 = __builtin_bit_cast(s16x8, paw[1]);
    // --- PV: single b128 B-frags from pi-ordered V LDS (pattern = K reads) ---
    __builtin_amdgcn_s_setprio(1);
#pragma unroll
    for (int ds = 0; ds < 4; ++ds) {
      const int row = ds * 16 + ln;
#pragma unroll
      for (int c = 0; c < 2; ++c) {
        const int off = (c * 64 + g * 16) ^ ((row & 7) << 4);
        const s16x8 vf = *(const s16x8*)((const char*)Vc + row * 128 + off);
        o[ds] = __builtin_amdgcn_mfma_f32_16x16x32_bf16(c == 0 ? pa0 : pa1, vf, o[ds], 0, 0, 0);
      }
    }
    __builtin_amdgcn_s_setprio(0);
    __syncthreads();  // drains prefetch (vmcnt) + protects buffer swap
  };

  for (int kt = 0; kt < 32; kt += 2) {
    body(Ks[0], Vs[0], Ks[1], Vs[1], kt);
    body(Ks[1], Vs[1], Ks[0], Vs[0], kt + 1);
  }

  // --- epilogue: deferred cross-lane l reduction, normalize, store bf16 ---
  // o reg r is q_local=4g+r, col=ds*16+ln; l lives at lane ln'=q_local (after g-reduce)
  l_lane += __shfl_xor(l_lane, 16);
  l_lane += __shfl_xor(l_lane, 32);
  float inv[4];
#pragma unroll
  for (int r = 0; r < 4; ++r) inv[r] = 1.0f / __shfl(l_lane, g * 4 + r);
  ushort* AOg = AO + ((size_t)b * Tt + qb * 64 + w * 16) * Ff + h * Dk;
#pragma unroll
  for (int ds = 0; ds < 4; ++ds)
#pragma unroll
    for (int r = 0; r < 4; ++r)
      AOg[(size_t)(g * 4 + r) * Ff + ds * 16 + ln] = f2bf(o[ds][r] * inv[r]);
}

// ---------------- host launch ----------------
extern "C" void kernel_launch(void* const* d_in, const int* in_sizes, int n_in,
                              void* d_out, int out_size, void* d_ws, size_t ws_size,
                              hipStream_t stream) {
  const float* query = (const float*)d_in[0];
  const float* key_  = (const float*)d_in[1];
  const float* value = (const float*)d_in[2];
  const int*   mask  = (const int*)d_in[3];
  const float* Wq = (const float*)d_in[4];  const float* bq = (const float*)d_in[5];
  const float* Wk = (const float*)d_in[6];  const float* bk = (const float*)d_in[7];
  const float* Wv = (const float*)d_in[8];  const float* bv = (const float*)d_in[9];
  const float* Wo = (const float*)d_in[10]; const float* bo = (const float*)d_in[11];
  float* Out = (float*)d_out;

  constexpr size_t SZ_X = (size_t)Mm * Ff * 2;  // 8 MB bf16 matrix
  constexpr size_t SZ_W = (size_t)Ff * Ff * 2;  // 2 MB bf16 weight
  uintptr_t p = (uintptr_t)d_ws;
  auto alloc = [&](size_t sz) { void* r = (void*)p; p += (sz + 255) & ~(size_t)255; return r; };
  ushort* Xq = (ushort*)alloc(SZ_X);
  ushort* Xk = (ushort*)alloc(SZ_X);
  ushort* Xv = (ushort*)alloc(SZ_X);
  ushort* Wqt = (ushort*)alloc(SZ_W);
  ushort* Wkt = (ushort*)alloc(SZ_W);
  ushort* Wvt = (ushort*)alloc(SZ_W);
  ushort* Wot = (ushort*)alloc(SZ_W);
  ushort* Qp  = (ushort*)alloc(SZ_X);
  ushort* Kp  = (ushort*)alloc(SZ_X);
  ushort* Vpt = (ushort*)alloc(SZ_X);  // [b][d][kv], pi-ordered columns, written by qkv_gemm z=2
  int* flags = (int*)alloc((size_t)Bb * 32 * 32 * 4);
  ushort* AO = Xq;  // alias: flash output (Xq dead after qkv_gemm)

  const int n8 = Mm * Ff / 8;  // 524288
  cvt3_kernel<<<dim3(2048, 3), 256, 0, stream>>>(query, key_, value, Xq, Xk, Xv, n8);
  wtrans_kernel<<<dim3(16, 16, 4), 256, 0, stream>>>(Wq, Wk, Wv, Wo, Wqt, Wkt, Wvt, Wot);
  maskflag_kernel<<<dim3(32, 32, 2), 256, 0, stream>>>(mask, flags);
  qkv_gemm_kernel<<<dim3(8, 32, 3), 256, 0, stream>>>(Xq, Xk, Xv, Wqt, Wkt, Wvt, bq, bk, bv, Qp, Kp, Vpt);
  flash_kernel<<<dim3(32, 16, 2), 256, 0, stream>>>(Qp, Kp, Vpt, flags, mask, AO);
  out_gemm_kernel<<<dim3(8, 32), 256, 0, stream>>>(AO, Wot, bo, Out);
}

// Round 3
// 153.980 us; speedup vs baseline: 1.2031x; 1.2031x over previous
//
#include <hip/hip_runtime.h>
#include <hip/hip_bf16.h>
#include <stdint.h>

typedef float  f32x4 __attribute__((ext_vector_type(4)));
typedef short  s16x8 __attribute__((ext_vector_type(8)));
typedef short  s16x4 __attribute__((ext_vector_type(4)));
typedef int    i32x4 __attribute__((ext_vector_type(4)));

#define DI __device__ __forceinline__

constexpr int Bb = 2, Tt = 2048, Ff = 1024, Hh = 16, Dk = 64;
constexpr int Mm = Bb * Tt;  // 4096 rows
constexpr float LOG2E = 1.44269504088896340736f;

DI ushort f2bf(float f) {  // round-to-nearest-even f32 -> bf16 (raw bits)
  unsigned u = __float_as_uint(f);
  unsigned r = (u + 0x7fffu + ((u >> 16) & 1u)) >> 16;
  return (ushort)r;
}

DI int cvt_pk_bf16(float lo, float hi) {  // packed f32x2 -> bf16x2 (v_cvt_pk_bf16_f32)
  __hip_bfloat162 t = __float22bfloat162_rn(make_float2(lo, hi));
  int w;
  __builtin_memcpy(&w, &t, 4);
  return w;
}

DI void gload16(const void* g, void* l) {  // async global->LDS, 16B/lane, dst = wave-uniform base + lane*16
  __builtin_amdgcn_global_load_lds(
      (__attribute__((address_space(1))) void*)g,
      (__attribute__((address_space(3))) void*)l, 16, 0, 0);
}

// ---------------- f32 -> bf16 convert, 3 tensors in one launch ----------------
__global__ __launch_bounds__(256) void cvt3_kernel(const float* __restrict__ s0, const float* __restrict__ s1,
                                                   const float* __restrict__ s2, ushort* __restrict__ d0,
                                                   ushort* __restrict__ d1, ushort* __restrict__ d2, int n8) {
  const float* src = blockIdx.y == 0 ? s0 : (blockIdx.y == 1 ? s1 : s2);
  ushort* dst = blockIdx.y == 0 ? d0 : (blockIdx.y == 1 ? d1 : d2);
  int i = blockIdx.x * 256 + threadIdx.x;
  if (i >= n8) return;
  const float4* s4 = (const float4*)src + (size_t)i * 2;
  float4 a = s4[0], b = s4[1];
  s16x8 o;
  o[0] = (short)f2bf(a.x); o[1] = (short)f2bf(a.y); o[2] = (short)f2bf(a.z); o[3] = (short)f2bf(a.w);
  o[4] = (short)f2bf(b.x); o[5] = (short)f2bf(b.y); o[6] = (short)f2bf(b.z); o[7] = (short)f2bf(b.w);
  *((s16x8*)dst + i) = o;
}

// ---------------- weight transpose+convert: W[k][n] f32 -> Wt[n][k] bf16 ----------------
__global__ __launch_bounds__(256) void wtrans_kernel(const float* __restrict__ W0, const float* __restrict__ W1,
                                                     const float* __restrict__ W2, const float* __restrict__ W3,
                                                     ushort* __restrict__ Wt0, ushort* __restrict__ Wt1,
                                                     ushort* __restrict__ Wt2, ushort* __restrict__ Wt3) {
  const float* W; ushort* Wt;
  switch (blockIdx.z) {
    case 0: W = W0; Wt = Wt0; break;
    case 1: W = W1; Wt = Wt1; break;
    case 2: W = W2; Wt = Wt2; break;
    default: W = W3; Wt = Wt3; break;
  }
  __shared__ float tile[64][65];
  int k0 = blockIdx.y * 64, n0 = blockIdx.x * 64;
  int t = threadIdx.x, r = t >> 4, c4 = (t & 15) * 4;
#pragma unroll
  for (int i = 0; i < 4; i++) {
    int row = r + i * 16;
    const float4 v = *(const float4*)(W + (size_t)(k0 + row) * Ff + n0 + c4);
    tile[row][c4] = v.x; tile[row][c4 + 1] = v.y; tile[row][c4 + 2] = v.z; tile[row][c4 + 3] = v.w;
  }
  __syncthreads();
#pragma unroll
  for (int i = 0; i < 4; i++) {
    int n = r + i * 16;
    s16x4 o;
#pragma unroll
    for (int j = 0; j < 4; j++) o[j] = (short)f2bf(tile[c4 + j][n]);
    *(s16x4*)(Wt + (size_t)(n0 + n) * Ff + k0 + c4) = o;
  }
}

// ---------------- mask tile summary: flag=1 iff whole 64x64 tile > 0 ----------------
__global__ __launch_bounds__(256) void maskflag_kernel(const int* __restrict__ mask, int* __restrict__ flags) {
  int kb = blockIdx.x, qb = blockIdx.y, b = blockIdx.z;
  int t = threadIdx.x;
  __shared__ int s;
  if (t == 0) s = 1;
  __syncthreads();
  int ok = 1;
#pragma unroll
  for (int i = 0; i < 4; i++) {
    int row = qb * 64 + (t >> 4) + i * 16;
    const int4 v = *(const int4*)(mask + ((size_t)b * Tt + row) * Tt + kb * 64 + (t & 15) * 4);
    ok &= (v.x > 0) & (v.y > 0) & (v.z > 0) & (v.w > 0);
  }
  atomicAnd(&s, ok);
  __syncthreads();
  if (t == 0) flags[(b * 32 + qb) * 32 + kb] = s;
}

// ---------------- bf16 GEMM, C = A[M,K] * Bt[N,K]^T (+bias)*scale ----------------
// T3-minimum 2-phase: BOTH operands double-buffered in XOR-swizzled LDS; each K-step issues
// STAGE(k+1) first (async gload_lds), then ds_read+MFMA on tile k, then ONE barrier whose
// vmcnt(0) drain overlaps a full compute phase. (Round-2 lesson: latency-bound, not conflict-bound.)
// mode 0: f32 row-major out. mode 1: bf16 row-major out. mode 2: bf16 V-fragment layout
//   (Vpt[(b*Ff+n)][kv], columns pi-permuted per 64-block: kv=32c+16f+4g+r stored at p=32c+8g+4f+r).
DI void gemm_core(const ushort* __restrict__ A, const ushort* __restrict__ Bt,
                  const float* __restrict__ bias, void* __restrict__ Cout, float scale, int mode,
                  int m0, int n0) {
  __shared__ ushort Ads[2][128 * 64];  // 32 KB (dbuf A)
  __shared__ ushort Bds[2][128 * 64];  // 32 KB (dbuf B)
  const int tid = threadIdx.x, lane = tid & 63, w = tid >> 6;
  const int wr = w >> 1, wc = w & 1;
  const int g = lane >> 4, ln = lane & 15;
  const int srow = lane >> 3;
  const int swzch = ((lane & 7) ^ srow) * 8;  // inverse-swizzled source chunk (ushorts)

  f32x4 acc[4][4];
#pragma unroll
  for (int m = 0; m < 4; m++)
#pragma unroll
    for (int n = 0; n < 4; n++) acc[m][n] = (f32x4){0.f, 0.f, 0.f, 0.f};

  // prologue: stage K-tile 0 into buffer 0 (pre-swizzled source, linear LDS dst)
#pragma unroll
  for (int it = 0; it < 4; ++it) {
    const int row = w * 32 + it * 8;
    gload16(A + (size_t)(m0 + row + srow) * Ff + swzch, Ads[0] + row * 64);
    gload16(Bt + (size_t)(n0 + row + srow) * Ff + swzch, Bds[0] + row * 64);
  }
  __syncthreads();

  for (int kk = 0; kk < 16; ++kk) {
    const int cur = kk & 1;
    const int k0 = kk * 64;
    // phase 1: issue next tile's async loads FIRST (latency hides under compute below)
    if (kk < 15) {
#pragma unroll
      for (int it = 0; it < 4; ++it) {
        const int row = w * 32 + it * 8;
        gload16(A + (size_t)(m0 + row + srow) * Ff + k0 + 64 + swzch, Ads[cur ^ 1] + row * 64);
        gload16(Bt + (size_t)(n0 + row + srow) * Ff + k0 + 64 + swzch, Bds[cur ^ 1] + row * 64);
      }
    }
    // phase 2: swizzled fragment reads (conflict-free, verified r2) + MFMA on current tile
    s16x8 af[4][2], bf[4][2];
#pragma unroll
    for (int m = 0; m < 4; m++)
#pragma unroll
      for (int c = 0; c < 2; c++) {
        const int ra = wr * 64 + m * 16 + ln;
        const int off = (c * 64 + g * 16) ^ ((ra & 7) << 4);
        af[m][c] = *(const s16x8*)((const char*)(Ads[cur]) + ra * 128 + off);
      }
#pragma unroll
    for (int n = 0; n < 4; n++)
#pragma unroll
      for (int c = 0; c < 2; c++) {
        const int rb = wc * 64 + n * 16 + ln;
        const int off = (c * 64 + g * 16) ^ ((rb & 7) << 4);
        bf[n][c] = *(const s16x8*)((const char*)(Bds[cur]) + rb * 128 + off);
      }
#pragma unroll
    for (int m = 0; m < 4; m++)
#pragma unroll
      for (int n = 0; n < 4; n++)
#pragma unroll
        for (int c = 0; c < 2; c++)
          acc[m][n] = __builtin_amdgcn_mfma_f32_16x16x32_bf16(af[m][c], bf[n][c], acc[m][n], 0, 0, 0);
    // single barrier per step: drains prefetch vmcnt + protects buffer swap
    if (kk < 15) __syncthreads();
  }
#pragma unroll
  for (int m = 0; m < 4; m++) {
    const int r0 = m0 + wr * 64 + m * 16 + g * 4;
#pragma unroll
    for (int n = 0; n < 4; n++) {
      const int col = n0 + wc * 64 + n * 16 + ln;
      const float bv = bias[col];
      if (mode == 2) {
        // V-fragment store: batch bb, row-in-batch rb, pi^-1 on kv within 64-block
        const int bb = r0 >> 11, rb = r0 & 2047;
        const int x = rb & 63;
        const int pbase = (x & 0x20) | ((x & 0x0C) << 1) | ((x & 0x10) >> 2);
        s16x4 o4;
#pragma unroll
        for (int r = 0; r < 4; r++) o4[r] = (short)f2bf(acc[m][n][r] + bv);
        *(s16x4*)((ushort*)Cout + ((size_t)bb * Ff + col) * Tt + (rb & ~63) + pbase) = o4;
      } else {
#pragma unroll
        for (int r = 0; r < 4; r++) {
          const float val = (acc[m][n][r] + bv) * scale;
          if (mode == 1)
            ((ushort*)Cout)[(size_t)(r0 + r) * Ff + col] = f2bf(val);
          else
            ((float*)Cout)[(size_t)(r0 + r) * Ff + col] = val;
        }
      }
    }
  }
}

__global__ __launch_bounds__(256) void qkv_gemm_kernel(
    const ushort* __restrict__ Xq, const ushort* __restrict__ Xk, const ushort* __restrict__ Xv,
    const ushort* __restrict__ Wqt, const ushort* __restrict__ Wkt, const ushort* __restrict__ Wvt,
    const float* __restrict__ bq, const float* __restrict__ bk, const float* __restrict__ bv,
    ushort* __restrict__ Qb, ushort* __restrict__ Kb, ushort* __restrict__ Vpt) {
  // T1: XCD-chunked bijective block swizzle (768 blocks -> 96 contiguous per XCD)
  const int lin = blockIdx.x + 8 * blockIdx.y + 256 * blockIdx.z;
  const int work = (lin & 7) * 96 + (lin >> 3);
  const int z = work >> 8;
  const int r = work & 255;
  const int m0 = (r >> 3) * 128, n0 = (r & 7) * 128;
  const ushort* A = z == 0 ? Xq : (z == 1 ? Xk : Xv);
  const ushort* Wt = z == 0 ? Wqt : (z == 1 ? Wkt : Wvt);
  const float* bias = z == 0 ? bq : (z == 1 ? bk : bv);
  void* C = z == 0 ? (void*)Qb : (z == 1 ? (void*)Kb : (void*)Vpt);
  // z==0: fold 1/sqrt(64) AND log2(e) into Q so softmax runs in exp2 domain
  const float scale = z == 0 ? 0.125f * LOG2E : 1.0f;
  gemm_core(A, Wt, bias, C, scale, z == 2 ? 2 : 1, m0, n0);
}

__global__ __launch_bounds__(256) void out_gemm_kernel(const ushort* __restrict__ AO,
                                                       const ushort* __restrict__ Wot,
                                                       const float* __restrict__ bo,
                                                       float* __restrict__ Out) {
  // T1: XCD-chunked bijective block swizzle (256 blocks -> 32 contiguous per XCD)
  const int lin = blockIdx.x + 8 * blockIdx.y;
  const int work = (lin & 7) * 32 + (lin >> 3);
  const int m0 = (work >> 3) * 128, n0 = (work & 7) * 128;
  gemm_core(AO, Wot, bo, Out, 1.0f, 0, m0, n0);
}

// ---------------- flash attention (max-free exp2-domain softmax) ----------------
// grid (qb=32, h=16, b=2), 256 thr (4 waves). BQ=64 (16 q-rows/wave), BK=64, D=64.
// S'^T = mfma(K_frag, Q_frag), scores already in log2 domain (Q pre-scaled by 0.125*log2e).
// Score magnitudes are bounded (|s_log2| << 127) so p = exp2(s) RAW is exact softmax up to a
// global 2^m factor that cancels in o/l: no max tracking, no rescale, no in-loop shuffles.
// lane (g,ln): q = w*16+ln, kv(sf[ks][r]) = kt*64 + 16ks + 4g + r.
// PV sigma k-slots on BOTH operands: slot (c,g,i=4f+r) <-> kv = 32c+16f+4g+r;
//   A-op packed in-register via v_cvt_pk; B-op = single b128 from pi-ordered d-major V LDS.
__global__ __launch_bounds__(256) void flash_kernel(
    const ushort* __restrict__ Qb, const ushort* __restrict__ Kb, const ushort* __restrict__ Vpt,
    const int* __restrict__ flags, const int* __restrict__ mask, ushort* __restrict__ AO) {
  __shared__ ushort Ks[2][64 * 64];
  __shared__ ushort Vs[2][64 * 64];
  // T1: XCD-chunked bijective block swizzle (1024 blocks -> 128 per XCD = 4 heads' KV, L2-fit)
  const int lin = blockIdx.x + 32 * (blockIdx.y + 16 * blockIdx.z);
  const int work = (lin & 7) * 128 + (lin >> 3);
  const int qb = work & 31, h = (work >> 5) & 15, b = work >> 9;
  const int tid = threadIdx.x, lane = tid & 63, w = tid >> 6;
  const int g = lane >> 4, ln = lane & 15;

  const ushort* Qg = Qb + ((size_t)b * Tt + qb * 64) * Ff + h * Dk;
  const ushort* Kg = Kb + ((size_t)b * Tt) * Ff + h * Dk;
  const ushort* Vg = Vpt + (size_t)(b * Ff + h * Dk) * Tt;  // rows d, stride Tt, cols pi-ordered

  const int srow = lane >> 3;
  const int swzch = ((lane & 7) ^ srow) * 8;  // inverse-swizzled source chunk (ushorts)

  // prologue: stage tile 0 (K,V)
#pragma unroll
  for (int it = 0; it < 2; ++it) {
    const int row = w * 16 + it * 8;
    gload16(Kg + (size_t)(row + srow) * Ff + swzch, Ks[0] + row * 64);
    gload16(Vg + (size_t)(row + srow) * Tt + swzch, Vs[0] + row * 64);
  }
  // preload mask-tile bitmask (bit kt set => tile needs masking)
  const int* flagrow = flags + (b * 32 + qb) * 32;
  const int myflag = (lane < 32) ? flagrow[lane] : 1;

  // Q fragments DIRECT from global (one-time read, no LDS round-trip):
  // qf[c] = Q[q=w*16+ln][d = c*32+g*8 ..+7]
  s16x8 qf[2];
  {
    const ushort* Qrow = Qg + (size_t)(w * 16 + ln) * Ff;
    qf[0] = *(const s16x8*)(Qrow + g * 8);
    qf[1] = *(const s16x8*)(Qrow + 32 + g * 8);
  }
  __syncthreads();
  const unsigned long long bm = __ballot(myflag == 0);

  float l_lane = 0.f;  // lane-local partial softmax denominator (this lane's kv slots for q=w*16+ln)
  f32x4 o[4];
#pragma unroll
  for (int ds = 0; ds < 4; ds++) o[ds] = (f32x4){0.f, 0.f, 0.f, 0.f};

  auto body = [&](const ushort* Kc, const ushort* Vc, ushort* Kn, ushort* Vn, int kt) {
    // --- prefetch tile kt+1 into next buffers (overlaps with compute below) ---
    if (kt + 1 < 32) {
      const ushort* Kg2 = Kg + (size_t)(kt + 1) * 64 * Ff;
      const ushort* Vg2 = Vg + (size_t)(kt + 1) * 64;
#pragma unroll
      for (int it = 0; it < 2; ++it) {
        const int row = w * 16 + it * 8;
        gload16(Kg2 + (size_t)(row + srow) * Ff + swzch, Kn + row * 64);
        gload16(Vg2 + (size_t)(row + srow) * Tt + swzch, Vn + row * 64);
      }
    }
    // --- S'^T = K * Q^T (log2 domain) ---
    f32x4 sf[4];
    __builtin_amdgcn_s_setprio(1);
#pragma unroll
    for (int ks = 0; ks < 4; ++ks) {
      f32x4 a = (f32x4){0.f, 0.f, 0.f, 0.f};
#pragma unroll
      for (int c = 0; c < 2; c++) {
        const int row = ks * 16 + ln;
        const int off = (c * 64 + g * 16) ^ ((row & 7) << 4);
        const s16x8 kf = *(const s16x8*)((const char*)Kc + row * 128 + off);
        a = __builtin_amdgcn_mfma_f32_16x16x32_bf16(kf, qf[c], a, 0, 0, 0);
      }
      sf[ks] = a;
    }
    __builtin_amdgcn_s_setprio(0);
    // --- mask (skipped for all-positive tiles); masked scores -> -10000 -> exp2 -> 0 ---
    if ((bm >> kt) & 1ull) {
      const int qg_ = qb * 64 + w * 16 + ln;
#pragma unroll
      for (int ks = 0; ks < 4; ++ks) {
        const int4 mv = *(const int4*)(mask + ((size_t)b * Tt + qg_) * Tt + kt * 64 + ks * 16 + g * 4);
        if (mv.x <= 0) sf[ks][0] = -10000.f;
        if (mv.y <= 0) sf[ks][1] = -10000.f;
        if (mv.z <= 0) sf[ks][2] = -10000.f;
        if (mv.w <= 0) sf[ks][3] = -10000.f;
      }
    }
    // --- raw exp2 (no max subtraction) + lane-local denominator partials ---
    float s0 = 0.f, s1 = 0.f;
#pragma unroll
    for (int ks = 0; ks < 4; ++ks) {
#pragma unroll
      for (int r = 0; r < 2; ++r) {
        const float p0 = __builtin_amdgcn_exp2f(sf[ks][2 * r]);
        const float p1 = __builtin_amdgcn_exp2f(sf[ks][2 * r + 1]);
        sf[ks][2 * r] = p0; sf[ks][2 * r + 1] = p1;
        s0 += p0; s1 += p1;
      }
    }
    l_lane += s0 + s1;
    // --- pack P A-frags via v_cvt_pk: word w of pa[c] = slots (2w,2w+1), i=4f+r ---
    i32x4 paw[2];
#pragma unroll
    for (int c = 0; c < 2; c++)
#pragma unroll
      for (int f = 0; f < 2; f++)
#pragma unroll
        for (int hh = 0; hh < 2; hh++)
          paw[c][f * 2 + hh] = cvt_pk_bf16(sf[2 * c + f][2 * hh], sf[2 * c + f][2 * hh + 1]);
    const s16x8 pa0 = __builtin_bit_cast(s16x8, paw[0]);
    const s16x8 pa1 = __builtin_bit_cast(s16x8, paw[1]);
    // --- PV: single b128 B-frags from pi-ordered V LDS (pattern = K reads) ---
    __builtin_amdgcn_s_setprio(1);
#pragma unroll
    for (int ds = 0; ds < 4; ++ds) {
      const int row = ds * 16 + ln;
#pragma unroll
      for (int c = 0; c < 2; ++c) {
        const int off = (c * 64 + g * 16) ^ ((row & 7) << 4);
        const s16x8 vf = *(const s16x8*)((const char*)Vc + row * 128 + off);
        o[ds] = __builtin_amdgcn_mfma_f32_16x16x32_bf16(c == 0 ? pa0 : pa1, vf, o[ds], 0, 0, 0);
      }
    }
    __builtin_amdgcn_s_setprio(0);
    __syncthreads();  // drains prefetch (vmcnt) + protects buffer swap
  };

  for (int kt = 0; kt < 32; kt += 2) {
    body(Ks[0], Vs[0], Ks[1], Vs[1], kt);
    body(Ks[1], Vs[1], Ks[0], Vs[0], kt + 1);
  }

  // --- epilogue: deferred cross-lane l reduction, normalize, store bf16 ---
  // o reg r is q_local=4g+r, col=ds*16+ln; l lives at lane ln'=q_local (after g-reduce)
  l_lane += __shfl_xor(l_lane, 16);
  l_lane += __shfl_xor(l_lane, 32);
  float inv[4];
#pragma unroll
  for (int r = 0; r < 4; ++r) inv[r] = 1.0f / __shfl(l_lane, g * 4 + r);
  ushort* AOg = AO + ((size_t)b * Tt + qb * 64 + w * 16) * Ff + h * Dk;
#pragma unroll
  for (int ds = 0; ds < 4; ++ds)
#pragma unroll
    for (int r = 0; r < 4; ++r)
      AOg[(size_t)(g * 4 + r) * Ff + ds * 16 + ln] = f2bf(o[ds][r] * inv[r]);
}

// ---------------- host launch ----------------
extern "C" void kernel_launch(void* const* d_in, const int* in_sizes, int n_in,
                              void* d_out, int out_size, void* d_ws, size_t ws_size,
                              hipStream_t stream) {
  const float* query = (const float*)d_in[0];
  const float* key_  = (const float*)d_in[1];
  const float* value = (const float*)d_in[2];
  const int*   mask  = (const int*)d_in[3];
  const float* Wq = (const float*)d_in[4];  const float* bq = (const float*)d_in[5];
  const float* Wk = (const float*)d_in[6];  const float* bk = (const float*)d_in[7];
  const float* Wv = (const float*)d_in[8];  const float* bv = (const float*)d_in[9];
  const float* Wo = (const float*)d_in[10]; const float* bo = (const float*)d_in[11];
  float* Out = (float*)d_out;

  constexpr size_t SZ_X = (size_t)Mm * Ff * 2;  // 8 MB bf16 matrix
  constexpr size_t SZ_W = (size_t)Ff * Ff * 2;  // 2 MB bf16 weight
  uintptr_t p = (uintptr_t)d_ws;
  auto alloc = [&](size_t sz) { void* r = (void*)p; p += (sz + 255) & ~(size_t)255; return r; };
  ushort* Xq = (ushort*)alloc(SZ_X);
  ushort* Xk = (ushort*)alloc(SZ_X);
  ushort* Xv = (ushort*)alloc(SZ_X);
  ushort* Wqt = (ushort*)alloc(SZ_W);
  ushort* Wkt = (ushort*)alloc(SZ_W);
  ushort* Wvt = (ushort*)alloc(SZ_W);
  ushort* Wot = (ushort*)alloc(SZ_W);
  ushort* Qp  = (ushort*)alloc(SZ_X);
  ushort* Kp  = (ushort*)alloc(SZ_X);
  ushort* Vpt = (ushort*)alloc(SZ_X);  // [b][d][kv], pi-ordered columns, written by qkv_gemm z=2
  int* flags = (int*)alloc((size_t)Bb * 32 * 32 * 4);
  ushort* AO = Xq;  // alias: flash output (Xq dead after qkv_gemm)

  const int n8 = Mm * Ff / 8;  // 524288
  cvt3_kernel<<<dim3(2048, 3), 256, 0, stream>>>(query, key_, value, Xq, Xk, Xv, n8);
  wtrans_kernel<<<dim3(16, 16, 4), 256, 0, stream>>>(Wq, Wk, Wv, Wo, Wqt, Wkt, Wvt, Wot);
  maskflag_kernel<<<dim3(32, 32, 2), 256, 0, stream>>>(mask, flags);
  qkv_gemm_kernel<<<dim3(8, 32, 3), 256, 0, stream>>>(Xq, Xk, Xv, Wqt, Wkt, Wvt, bq, bk, bv, Qp, Kp, Vpt);
  flash_kernel<<<dim3(32, 16, 2), 256, 0, stream>>>(Qp, Kp, Vpt, flags, mask, AO);
  out_gemm_kernel<<<dim3(8, 32), 256, 0, stream>>>(AO, Wot, bo, Out);
}

// Round 4
// 145.614 us; speedup vs baseline: 1.2723x; 1.0575x over previous
//
#include <hip/hip_runtime.h>
#include <hip/hip_bf16.h>
#include <stdint.h>

typedef float  f32x4 __attribute__((ext_vector_type(4)));
typedef short  s16x8 __attribute__((ext_vector_type(8)));
typedef short  s16x4 __attribute__((ext_vector_type(4)));
typedef int    i32x4 __attribute__((ext_vector_type(4)));

#define DI __device__ __forceinline__

constexpr int Bb = 2, Tt = 2048, Ff = 1024, Hh = 16, Dk = 64;
constexpr int Mm = Bb * Tt;  // 4096 rows
constexpr float LOG2E = 1.44269504088896340736f;

DI ushort f2bf(float f) {  // round-to-nearest-even f32 -> bf16 (raw bits)
  unsigned u = __float_as_uint(f);
  unsigned r = (u + 0x7fffu + ((u >> 16) & 1u)) >> 16;
  return (ushort)r;
}

DI int cvt_pk_bf16(float lo, float hi) {  // packed f32x2 -> bf16x2 (v_cvt_pk_bf16_f32)
  __hip_bfloat162 t = __float22bfloat162_rn(make_float2(lo, hi));
  int w;
  __builtin_memcpy(&w, &t, 4);
  return w;
}

DI void gload16(const void* g, void* l) {  // async global->LDS, 16B/lane, dst = wave-uniform base + lane*16
  __builtin_amdgcn_global_load_lds(
      (__attribute__((address_space(1))) void*)g,
      (__attribute__((address_space(3))) void*)l, 16, 0, 0);
}

// ---------------- f32 -> bf16 convert, 3 tensors in one launch ----------------
__global__ __launch_bounds__(256) void cvt3_kernel(const float* __restrict__ s0, const float* __restrict__ s1,
                                                   const float* __restrict__ s2, ushort* __restrict__ d0,
                                                   ushort* __restrict__ d1, ushort* __restrict__ d2, int n8) {
  const float* src = blockIdx.y == 0 ? s0 : (blockIdx.y == 1 ? s1 : s2);
  ushort* dst = blockIdx.y == 0 ? d0 : (blockIdx.y == 1 ? d1 : d2);
  int i = blockIdx.x * 256 + threadIdx.x;
  if (i >= n8) return;
  const float4* s4 = (const float4*)src + (size_t)i * 2;
  float4 a = s4[0], b = s4[1];
  s16x8 o;
  o[0] = (short)f2bf(a.x); o[1] = (short)f2bf(a.y); o[2] = (short)f2bf(a.z); o[3] = (short)f2bf(a.w);
  o[4] = (short)f2bf(b.x); o[5] = (short)f2bf(b.y); o[6] = (short)f2bf(b.z); o[7] = (short)f2bf(b.w);
  *((s16x8*)dst + i) = o;
}

// ---------------- weight transpose+convert: W[k][n] f32 -> Wt[n][k] bf16 ----------------
__global__ __launch_bounds__(256) void wtrans_kernel(const float* __restrict__ W0, const float* __restrict__ W1,
                                                     const float* __restrict__ W2, const float* __restrict__ W3,
                                                     ushort* __restrict__ Wt0, ushort* __restrict__ Wt1,
                                                     ushort* __restrict__ Wt2, ushort* __restrict__ Wt3) {
  const float* W; ushort* Wt;
  switch (blockIdx.z) {
    case 0: W = W0; Wt = Wt0; break;
    case 1: W = W1; Wt = Wt1; break;
    case 2: W = W2; Wt = Wt2; break;
    default: W = W3; Wt = Wt3; break;
  }
  __shared__ float tile[64][65];
  int k0 = blockIdx.y * 64, n0 = blockIdx.x * 64;
  int t = threadIdx.x, r = t >> 4, c4 = (t & 15) * 4;
#pragma unroll
  for (int i = 0; i < 4; i++) {
    int row = r + i * 16;
    const float4 v = *(const float4*)(W + (size_t)(k0 + row) * Ff + n0 + c4);
    tile[row][c4] = v.x; tile[row][c4 + 1] = v.y; tile[row][c4 + 2] = v.z; tile[row][c4 + 3] = v.w;
  }
  __syncthreads();
#pragma unroll
  for (int i = 0; i < 4; i++) {
    int n = r + i * 16;
    s16x4 o;
#pragma unroll
    for (int j = 0; j < 4; j++) o[j] = (short)f2bf(tile[c4 + j][n]);
    *(s16x4*)(Wt + (size_t)(n0 + n) * Ff + k0 + c4) = o;
  }
}

// ---------------- mask tile summary: flag=1 iff whole 64x64 tile > 0 ----------------
__global__ __launch_bounds__(256) void maskflag_kernel(const int* __restrict__ mask, int* __restrict__ flags) {
  int kb = blockIdx.x, qb = blockIdx.y, b = blockIdx.z;
  int t = threadIdx.x;
  __shared__ int s;
  if (t == 0) s = 1;
  __syncthreads();
  int ok = 1;
#pragma unroll
  for (int i = 0; i < 4; i++) {
    int row = qb * 64 + (t >> 4) + i * 16;
    const int4 v = *(const int4*)(mask + ((size_t)b * Tt + row) * Tt + kb * 64 + (t & 15) * 4);
    ok &= (v.x > 0) & (v.y > 0) & (v.z > 0) & (v.w > 0);
  }
  atomicAnd(&s, ok);
  __syncthreads();
  if (t == 0) flags[(b * 32 + qb) * 32 + kb] = s;
}

// ---------------- bf16 GEMM, C = A[M,K] * Bt[N,K]^T (+bias)*scale ----------------
// T3-minimum 2-phase: BOTH operands double-buffered in XOR-swizzled LDS; each K-step issues
// STAGE(k+1) first (async gload_lds), then ds_read+MFMA on tile k, then ONE barrier whose
// vmcnt(0) drain overlaps a full compute phase.
// mode 0: f32 row-major out. mode 1: bf16 row-major out. mode 2: bf16 V-fragment layout
//   (Vpt[(b*Ff+n)][kv], columns pi-permuted per 64-block: kv=32c+16f+4g+r stored at p=32c+8g+4f+r).
DI void gemm_core(const ushort* __restrict__ A, const ushort* __restrict__ Bt,
                  const float* __restrict__ bias, void* __restrict__ Cout, float scale, int mode,
                  int m0, int n0) {
  __shared__ ushort Ads[2][128 * 64];  // 32 KB (dbuf A)
  __shared__ ushort Bds[2][128 * 64];  // 32 KB (dbuf B)
  const int tid = threadIdx.x, lane = tid & 63, w = tid >> 6;
  const int wr = w >> 1, wc = w & 1;
  const int g = lane >> 4, ln = lane & 15;
  const int srow = lane >> 3;
  const int swzch = ((lane & 7) ^ srow) * 8;  // inverse-swizzled source chunk (ushorts)

  f32x4 acc[4][4];
#pragma unroll
  for (int m = 0; m < 4; m++)
#pragma unroll
    for (int n = 0; n < 4; n++) acc[m][n] = (f32x4){0.f, 0.f, 0.f, 0.f};

  // prologue: stage K-tile 0 into buffer 0 (pre-swizzled source, linear LDS dst)
#pragma unroll
  for (int it = 0; it < 4; ++it) {
    const int row = w * 32 + it * 8;
    gload16(A + (size_t)(m0 + row + srow) * Ff + swzch, Ads[0] + row * 64);
    gload16(Bt + (size_t)(n0 + row + srow) * Ff + swzch, Bds[0] + row * 64);
  }
  __syncthreads();

  for (int kk = 0; kk < 16; ++kk) {
    const int cur = kk & 1;
    const int k0 = kk * 64;
    // phase 1: issue next tile's async loads FIRST (latency hides under compute below)
    if (kk < 15) {
#pragma unroll
      for (int it = 0; it < 4; ++it) {
        const int row = w * 32 + it * 8;
        gload16(A + (size_t)(m0 + row + srow) * Ff + k0 + 64 + swzch, Ads[cur ^ 1] + row * 64);
        gload16(Bt + (size_t)(n0 + row + srow) * Ff + k0 + 64 + swzch, Bds[cur ^ 1] + row * 64);
      }
    }
    // phase 2: swizzled fragment reads (conflict-free) + MFMA on current tile
    s16x8 af[4][2], bf[4][2];
#pragma unroll
    for (int m = 0; m < 4; m++)
#pragma unroll
      for (int c = 0; c < 2; c++) {
        const int ra = wr * 64 + m * 16 + ln;
        const int off = (c * 64 + g * 16) ^ ((ra & 7) << 4);
        af[m][c] = *(const s16x8*)((const char*)(Ads[cur]) + ra * 128 + off);
      }
#pragma unroll
    for (int n = 0; n < 4; n++)
#pragma unroll
      for (int c = 0; c < 2; c++) {
        const int rb = wc * 64 + n * 16 + ln;
        const int off = (c * 64 + g * 16) ^ ((rb & 7) << 4);
        bf[n][c] = *(const s16x8*)((const char*)(Bds[cur]) + rb * 128 + off);
      }
#pragma unroll
    for (int m = 0; m < 4; m++)
#pragma unroll
      for (int n = 0; n < 4; n++)
#pragma unroll
        for (int c = 0; c < 2; c++)
          acc[m][n] = __builtin_amdgcn_mfma_f32_16x16x32_bf16(af[m][c], bf[n][c], acc[m][n], 0, 0, 0);
    // single barrier per step: drains prefetch vmcnt + protects buffer swap
    if (kk < 15) __syncthreads();
  }
#pragma unroll
  for (int m = 0; m < 4; m++) {
    const int r0 = m0 + wr * 64 + m * 16 + g * 4;
#pragma unroll
    for (int n = 0; n < 4; n++) {
      const int col = n0 + wc * 64 + n * 16 + ln;
      const float bv = bias[col];
      if (mode == 2) {
        // V-fragment store: batch bb, row-in-batch rb, pi^-1 on kv within 64-block
        const int bb = r0 >> 11, rb = r0 & 2047;
        const int x = rb & 63;
        const int pbase = (x & 0x20) | ((x & 0x0C) << 1) | ((x & 0x10) >> 2);
        s16x4 o4;
#pragma unroll
        for (int r = 0; r < 4; r++) o4[r] = (short)f2bf(acc[m][n][r] + bv);
        *(s16x4*)((ushort*)Cout + ((size_t)bb * Ff + col) * Tt + (rb & ~63) + pbase) = o4;
      } else {
#pragma unroll
        for (int r = 0; r < 4; r++) {
          const float val = (acc[m][n][r] + bv) * scale;
          if (mode == 1)
            ((ushort*)Cout)[(size_t)(r0 + r) * Ff + col] = f2bf(val);
          else
            ((float*)Cout)[(size_t)(r0 + r) * Ff + col] = val;
        }
      }
    }
  }
}

__global__ __launch_bounds__(256) void qkv_gemm_kernel(
    const ushort* __restrict__ Xq, const ushort* __restrict__ Xk, const ushort* __restrict__ Xv,
    const ushort* __restrict__ Wqt, const ushort* __restrict__ Wkt, const ushort* __restrict__ Wvt,
    const float* __restrict__ bq, const float* __restrict__ bk, const float* __restrict__ bv,
    ushort* __restrict__ Qb, ushort* __restrict__ Kb, ushort* __restrict__ Vpt) {
  // T1: XCD-chunked bijective block swizzle (768 blocks -> 96 contiguous per XCD)
  const int lin = blockIdx.x + 8 * blockIdx.y + 256 * blockIdx.z;
  const int work = (lin & 7) * 96 + (lin >> 3);
  const int z = work >> 8;
  const int r = work & 255;
  const int m0 = (r >> 3) * 128, n0 = (r & 7) * 128;
  const ushort* A = z == 0 ? Xq : (z == 1 ? Xk : Xv);
  const ushort* Wt = z == 0 ? Wqt : (z == 1 ? Wkt : Wvt);
  const float* bias = z == 0 ? bq : (z == 1 ? bk : bv);
  void* C = z == 0 ? (void*)Qb : (z == 1 ? (void*)Kb : (void*)Vpt);
  // z==0: fold 1/sqrt(64) AND log2(e) into Q so softmax runs in exp2 domain
  const float scale = z == 0 ? 0.125f * LOG2E : 1.0f;
  gemm_core(A, Wt, bias, C, scale, z == 2 ? 2 : 1, m0, n0);
}

__global__ __launch_bounds__(256) void out_gemm_kernel(const ushort* __restrict__ AO,
                                                       const ushort* __restrict__ Wot,
                                                       const float* __restrict__ bo,
                                                       float* __restrict__ Out) {
  // T1: XCD-chunked bijective block swizzle (256 blocks -> 32 contiguous per XCD)
  const int lin = blockIdx.x + 8 * blockIdx.y;
  const int work = (lin & 7) * 32 + (lin >> 3);
  const int m0 = (work >> 3) * 128, n0 = (work & 7) * 128;
  gemm_core(AO, Wot, bo, Out, 1.0f, 0, m0, n0);
}

// ---------------- flash attention (max-free exp2 softmax, QBLK=128) ----------------
// grid (qb=16, h=16, b=2), 256 thr (4 waves). BQ=128 (32 q-rows/wave in TWO 16-row groups),
// BK=64, D=64. Each K/V fragment read from LDS feeds TWO MFMAs (one per q-group) ->
// ds_read:MFMA = 1:2 (round-3 lesson: flash was LDS-unit-throughput-bound at 1:1).
// S'^T = mfma(K_frag, Q_frag), scores in log2 domain (Q pre-scaled by 0.125*log2e);
// raw exp2, lane-local l, cross-lane reduce deferred to epilogue.
// lane (g,ln): group j covers q = qb*128 + j*64 + w*16 + ln; kv(sf[ks][r]) = kt*64+16ks+4g+r.
// PV sigma k-slots on BOTH operands: slot (c,g,i=4f+r) <-> kv = 32c+16f+4g+r;
//   A-op packed in-register via v_cvt_pk; B-op = single b128 from pi-ordered d-major V LDS.
__global__ __launch_bounds__(256) void flash_kernel(
    const ushort* __restrict__ Qb, const ushort* __restrict__ Kb, const ushort* __restrict__ Vpt,
    const int* __restrict__ flags, const int* __restrict__ mask, ushort* __restrict__ AO) {
  __shared__ ushort Ks[2][64 * 64];
  __shared__ ushort Vs[2][64 * 64];
  // T1: XCD-chunked bijective block swizzle (512 blocks -> 64 per XCD = 4 heads' KV, L2-fit)
  const int lin = blockIdx.x + 16 * (blockIdx.y + 16 * blockIdx.z);
  const int work = (lin & 7) * 64 + (lin >> 3);
  const int qb = work & 15, h = (work >> 4) & 15, b = work >> 8;
  const int tid = threadIdx.x, lane = tid & 63, w = tid >> 6;
  const int g = lane >> 4, ln = lane & 15;

  const ushort* Qg = Qb + ((size_t)b * Tt + qb * 128) * Ff + h * Dk;
  const ushort* Kg = Kb + ((size_t)b * Tt) * Ff + h * Dk;
  const ushort* Vg = Vpt + (size_t)(b * Ff + h * Dk) * Tt;  // rows d, stride Tt, cols pi-ordered

  const int srow = lane >> 3;
  const int swzch = ((lane & 7) ^ srow) * 8;  // inverse-swizzled source chunk (ushorts)

  // prologue: stage tile 0 (K,V)
#pragma unroll
  for (int it = 0; it < 2; ++it) {
    const int row = w * 16 + it * 8;
    gload16(Kg + (size_t)(row + srow) * Ff + swzch, Ks[0] + row * 64);
    gload16(Vg + (size_t)(row + srow) * Tt + swzch, Vs[0] + row * 64);
  }
  // preload mask-tile bitmasks for both 64-row q-groups (bit kt set => tile needs masking)
  const int* flagrow0 = flags + (b * 32 + qb * 2) * 32;
  const int f0 = (lane < 32) ? flagrow0[lane] : 1;
  const int f1 = (lane < 32) ? flagrow0[32 + lane] : 1;

  // Q fragments DIRECT from global (one-time read): qf{j}[c] = Q[j*64 + w*16+ln][c*32+g*8 ..+7]
  s16x8 qf0[2], qf1[2];
  {
    const ushort* Qrow0 = Qg + (size_t)(w * 16 + ln) * Ff;
    const ushort* Qrow1 = Qrow0 + (size_t)64 * Ff;
    qf0[0] = *(const s16x8*)(Qrow0 + g * 8);
    qf0[1] = *(const s16x8*)(Qrow0 + 32 + g * 8);
    qf1[0] = *(const s16x8*)(Qrow1 + g * 8);
    qf1[1] = *(const s16x8*)(Qrow1 + 32 + g * 8);
  }
  __syncthreads();
  const unsigned long long bm0 = __ballot(f0 == 0);
  const unsigned long long bm1 = __ballot(f1 == 0);

  float l0 = 0.f, l1 = 0.f;  // lane-local partial denominators (per q-group)
  f32x4 o0[4], o1[4];
#pragma unroll
  for (int ds = 0; ds < 4; ds++) { o0[ds] = (f32x4){0.f, 0.f, 0.f, 0.f}; o1[ds] = (f32x4){0.f, 0.f, 0.f, 0.f}; }

  auto body = [&](const ushort* Kc, const ushort* Vc, ushort* Kn, ushort* Vn, int kt) {
    // --- prefetch tile kt+1 into next buffers (overlaps with compute below) ---
    if (kt + 1 < 32) {
      const ushort* Kg2 = Kg + (size_t)(kt + 1) * 64 * Ff;
      const ushort* Vg2 = Vg + (size_t)(kt + 1) * 64;
#pragma unroll
      for (int it = 0; it < 2; ++it) {
        const int row = w * 16 + it * 8;
        gload16(Kg2 + (size_t)(row + srow) * Ff + swzch, Kn + row * 64);
        gload16(Vg2 + (size_t)(row + srow) * Tt + swzch, Vn + row * 64);
      }
    }
    // --- S'^T = K * Q^T (log2 domain); each kf feeds BOTH q-groups ---
    f32x4 sf0[4], sf1[4];
    __builtin_amdgcn_s_setprio(1);
#pragma unroll
    for (int ks = 0; ks < 4; ++ks) {
      f32x4 a0 = (f32x4){0.f, 0.f, 0.f, 0.f};
      f32x4 a1 = (f32x4){0.f, 0.f, 0.f, 0.f};
#pragma unroll
      for (int c = 0; c < 2; c++) {
        const int row = ks * 16 + ln;
        const int off = (c * 64 + g * 16) ^ ((row & 7) << 4);
        const s16x8 kf = *(const s16x8*)((const char*)Kc + row * 128 + off);
        a0 = __builtin_amdgcn_mfma_f32_16x16x32_bf16(kf, qf0[c], a0, 0, 0, 0);
        a1 = __builtin_amdgcn_mfma_f32_16x16x32_bf16(kf, qf1[c], a1, 0, 0, 0);
      }
      sf0[ks] = a0; sf1[ks] = a1;
    }
    __builtin_amdgcn_s_setprio(0);
    // --- mask (skipped for all-positive tiles); masked scores -> -10000 -> exp2 -> 0 ---
    if ((bm0 >> kt) & 1ull) {
      const int qg_ = qb * 128 + w * 16 + ln;
#pragma unroll
      for (int ks = 0; ks < 4; ++ks) {
        const int4 mv = *(const int4*)(mask + ((size_t)b * Tt + qg_) * Tt + kt * 64 + ks * 16 + g * 4);
        if (mv.x <= 0) sf0[ks][0] = -10000.f;
        if (mv.y <= 0) sf0[ks][1] = -10000.f;
        if (mv.z <= 0) sf0[ks][2] = -10000.f;
        if (mv.w <= 0) sf0[ks][3] = -10000.f;
      }
    }
    if ((bm1 >> kt) & 1ull) {
      const int qg_ = qb * 128 + 64 + w * 16 + ln;
#pragma unroll
      for (int ks = 0; ks < 4; ++ks) {
        const int4 mv = *(const int4*)(mask + ((size_t)b * Tt + qg_) * Tt + kt * 64 + ks * 16 + g * 4);
        if (mv.x <= 0) sf1[ks][0] = -10000.f;
        if (mv.y <= 0) sf1[ks][1] = -10000.f;
        if (mv.z <= 0) sf1[ks][2] = -10000.f;
        if (mv.w <= 0) sf1[ks][3] = -10000.f;
      }
    }
    // --- raw exp2 (no max subtraction) + lane-local denominator partials ---
    float a0 = 0.f, a1 = 0.f;
#pragma unroll
    for (int ks = 0; ks < 4; ++ks) {
#pragma unroll
      for (int r = 0; r < 4; ++r) {
        const float p0 = __builtin_amdgcn_exp2f(sf0[ks][r]);
        const float p1 = __builtin_amdgcn_exp2f(sf1[ks][r]);
        sf0[ks][r] = p0; sf1[ks][r] = p1;
        a0 += p0; a1 += p1;
      }
    }
    l0 += a0; l1 += a1;
    // --- pack P A-frags via v_cvt_pk: word w of pa{j}[c] = slots (2w,2w+1), i=4f+r ---
    i32x4 paw0[2], paw1[2];
#pragma unroll
    for (int c = 0; c < 2; c++)
#pragma unroll
      for (int f = 0; f < 2; f++)
#pragma unroll
        for (int hh = 0; hh < 2; hh++) {
          paw0[c][f * 2 + hh] = cvt_pk_bf16(sf0[2 * c + f][2 * hh], sf0[2 * c + f][2 * hh + 1]);
          paw1[c][f * 2 + hh] = cvt_pk_bf16(sf1[2 * c + f][2 * hh], sf1[2 * c + f][2 * hh + 1]);
        }
    const s16x8 pa00 = __builtin_bit_cast(s16x8, paw0[0]);
    const s16x8 pa01 = __builtin_bit_cast(s16x8, paw0[1]);
    const s16x8 pa10 = __builtin_bit_cast(s16x8, paw1[0]);
    const s16x8 pa11 = __builtin_bit_cast(s16x8, paw1[1]);
    // --- PV: single b128 B-frags from pi-ordered V LDS; each vf feeds BOTH q-groups ---
    __builtin_amdgcn_s_setprio(1);
#pragma unroll
    for (int ds = 0; ds < 4; ++ds) {
      const int row = ds * 16 + ln;
#pragma unroll
      for (int c = 0; c < 2; ++c) {
        const int off = (c * 64 + g * 16) ^ ((row & 7) << 4);
        const s16x8 vf = *(const s16x8*)((const char*)Vc + row * 128 + off);
        o0[ds] = __builtin_amdgcn_mfma_f32_16x16x32_bf16(c == 0 ? pa00 : pa01, vf, o0[ds], 0, 0, 0);
        o1[ds] = __builtin_amdgcn_mfma_f32_16x16x32_bf16(c == 0 ? pa10 : pa11, vf, o1[ds], 0, 0, 0);
      }
    }
    __builtin_amdgcn_s_setprio(0);
    __syncthreads();  // drains prefetch (vmcnt) + protects buffer swap
  };

  for (int kt = 0; kt < 32; kt += 2) {
    body(Ks[0], Vs[0], Ks[1], Vs[1], kt);
    body(Ks[1], Vs[1], Ks[0], Vs[0], kt + 1);
  }

  // --- epilogue: deferred cross-lane l reduction, normalize, store bf16 ---
  // o{j} reg r is q_local=4g+r, col=ds*16+ln; l lives at lane ln'=q_local (after g-reduce)
  l0 += __shfl_xor(l0, 16); l0 += __shfl_xor(l0, 32);
  l1 += __shfl_xor(l1, 16); l1 += __shfl_xor(l1, 32);
  float inv0[4], inv1[4];
#pragma unroll
  for (int r = 0; r < 4; ++r) {
    inv0[r] = 1.0f / __shfl(l0, g * 4 + r);
    inv1[r] = 1.0f / __shfl(l1, g * 4 + r);
  }
  ushort* AOg0 = AO + ((size_t)b * Tt + qb * 128 + w * 16) * Ff + h * Dk;
  ushort* AOg1 = AOg0 + (size_t)64 * Ff;
#pragma unroll
  for (int ds = 0; ds < 4; ++ds)
#pragma unroll
    for (int r = 0; r < 4; ++r) {
      AOg0[(size_t)(g * 4 + r) * Ff + ds * 16 + ln] = f2bf(o0[ds][r] * inv0[r]);
      AOg1[(size_t)(g * 4 + r) * Ff + ds * 16 + ln] = f2bf(o1[ds][r] * inv1[r]);
    }
}

// ---------------- host launch ----------------
extern "C" void kernel_launch(void* const* d_in, const int* in_sizes, int n_in,
                              void* d_out, int out_size, void* d_ws, size_t ws_size,
                              hipStream_t stream) {
  const float* query = (const float*)d_in[0];
  const float* key_  = (const float*)d_in[1];
  const float* value = (const float*)d_in[2];
  const int*   mask  = (const int*)d_in[3];
  const float* Wq = (const float*)d_in[4];  const float* bq = (const float*)d_in[5];
  const float* Wk = (const float*)d_in[6];  const float* bk = (const float*)d_in[7];
  const float* Wv = (const float*)d_in[8];  const float* bv = (const float*)d_in[9];
  const float* Wo = (const float*)d_in[10]; const float* bo = (const float*)d_in[11];
  float* Out = (float*)d_out;

  constexpr size_t SZ_X = (size_t)Mm * Ff * 2;  // 8 MB bf16 matrix
  constexpr size_t SZ_W = (size_t)Ff * Ff * 2;  // 2 MB bf16 weight
  uintptr_t p = (uintptr_t)d_ws;
  auto alloc = [&](size_t sz) { void* r = (void*)p; p += (sz + 255) & ~(size_t)255; return r; };
  ushort* Xq = (ushort*)alloc(SZ_X);
  ushort* Xk = (ushort*)alloc(SZ_X);
  ushort* Xv = (ushort*)alloc(SZ_X);
  ushort* Wqt = (ushort*)alloc(SZ_W);
  ushort* Wkt = (ushort*)alloc(SZ_W);
  ushort* Wvt = (ushort*)alloc(SZ_W);
  ushort* Wot = (ushort*)alloc(SZ_W);
  ushort* Qp  = (ushort*)alloc(SZ_X);
  ushort* Kp  = (ushort*)alloc(SZ_X);
  ushort* Vpt = (ushort*)alloc(SZ_X);  // [b][d][kv], pi-ordered columns, written by qkv_gemm z=2
  int* flags = (int*)alloc((size_t)Bb * 32 * 32 * 4);
  ushort* AO = Xq;  // alias: flash output (Xq dead after qkv_gemm)

  const int n8 = Mm * Ff / 8;  // 524288
  cvt3_kernel<<<dim3(2048, 3), 256, 0, stream>>>(query, key_, value, Xq, Xk, Xv, n8);
  wtrans_kernel<<<dim3(16, 16, 4), 256, 0, stream>>>(Wq, Wk, Wv, Wo, Wqt, Wkt, Wvt, Wot);
  maskflag_kernel<<<dim3(32, 32, 2), 256, 0, stream>>>(mask, flags);
  qkv_gemm_kernel<<<dim3(8, 32, 3), 256, 0, stream>>>(Xq, Xk, Xv, Wqt, Wkt, Wvt, bq, bk, bv, Qp, Kp, Vpt);
  flash_kernel<<<dim3(16, 16, 2), 256, 0, stream>>>(Qp, Kp, Vpt, flags, mask, AO);
  out_gemm_kernel<<<dim3(8, 32), 256, 0, stream>>>(AO, Wot, bo, Out);
}

// Round 5
// 144.020 us; speedup vs baseline: 1.2863x; 1.0111x over previous
//
#include <hip/hip_runtime.h>
#include <hip/hip_bf16.h>
#include <stdint.h>

typedef float  f32x4 __attribute__((ext_vector_type(4)));
typedef short  s16x8 __attribute__((ext_vector_type(8)));
typedef short  s16x4 __attribute__((ext_vector_type(4)));
typedef int    i32x4 __attribute__((ext_vector_type(4)));

#define DI __device__ __forceinline__

constexpr int Bb = 2, Tt = 2048, Ff = 1024, Hh = 16, Dk = 64;
constexpr int Mm = Bb * Tt;  // 4096 rows
constexpr float LOG2E = 1.44269504088896340736f;

DI ushort f2bf(float f) {  // round-to-nearest-even f32 -> bf16 (raw bits)
  unsigned u = __float_as_uint(f);
  unsigned r = (u + 0x7fffu + ((u >> 16) & 1u)) >> 16;
  return (ushort)r;
}

DI int cvt_pk_bf16(float lo, float hi) {  // packed f32x2 -> bf16x2 (v_cvt_pk_bf16_f32)
  __hip_bfloat162 t = __float22bfloat162_rn(make_float2(lo, hi));
  int w;
  __builtin_memcpy(&w, &t, 4);
  return w;
}

DI void gload16(const void* g, void* l) {  // async global->LDS, 16B/lane, dst = wave-uniform base + lane*16
  __builtin_amdgcn_global_load_lds(
      (__attribute__((address_space(1))) void*)g,
      (__attribute__((address_space(3))) void*)l, 16, 0, 0);
}

DI void wait_vm4() { asm volatile("s_waitcnt vmcnt(4)" ::: "memory"); }
DI void wait_vm0() { asm volatile("s_waitcnt vmcnt(0)" ::: "memory"); }

// ---------------- f32 -> bf16 convert, 3 tensors in one launch ----------------
__global__ __launch_bounds__(256) void cvt3_kernel(const float* __restrict__ s0, const float* __restrict__ s1,
                                                   const float* __restrict__ s2, ushort* __restrict__ d0,
                                                   ushort* __restrict__ d1, ushort* __restrict__ d2, int n8) {
  const float* src = blockIdx.y == 0 ? s0 : (blockIdx.y == 1 ? s1 : s2);
  ushort* dst = blockIdx.y == 0 ? d0 : (blockIdx.y == 1 ? d1 : d2);
  int i = blockIdx.x * 256 + threadIdx.x;
  if (i >= n8) return;
  const float4* s4 = (const float4*)src + (size_t)i * 2;
  float4 a = s4[0], b = s4[1];
  s16x8 o;
  o[0] = (short)f2bf(a.x); o[1] = (short)f2bf(a.y); o[2] = (short)f2bf(a.z); o[3] = (short)f2bf(a.w);
  o[4] = (short)f2bf(b.x); o[5] = (short)f2bf(b.y); o[6] = (short)f2bf(b.z); o[7] = (short)f2bf(b.w);
  *((s16x8*)dst + i) = o;
}

// ---------------- weight transpose+convert: W[k][n] f32 -> Wt[n][k] bf16 ----------------
__global__ __launch_bounds__(256) void wtrans_kernel(const float* __restrict__ W0, const float* __restrict__ W1,
                                                     const float* __restrict__ W2, const float* __restrict__ W3,
                                                     ushort* __restrict__ Wt0, ushort* __restrict__ Wt1,
                                                     ushort* __restrict__ Wt2, ushort* __restrict__ Wt3) {
  const float* W; ushort* Wt;
  switch (blockIdx.z) {
    case 0: W = W0; Wt = Wt0; break;
    case 1: W = W1; Wt = Wt1; break;
    case 2: W = W2; Wt = Wt2; break;
    default: W = W3; Wt = Wt3; break;
  }
  __shared__ float tile[64][65];
  int k0 = blockIdx.y * 64, n0 = blockIdx.x * 64;
  int t = threadIdx.x, r = t >> 4, c4 = (t & 15) * 4;
#pragma unroll
  for (int i = 0; i < 4; i++) {
    int row = r + i * 16;
    const float4 v = *(const float4*)(W + (size_t)(k0 + row) * Ff + n0 + c4);
    tile[row][c4] = v.x; tile[row][c4 + 1] = v.y; tile[row][c4 + 2] = v.z; tile[row][c4 + 3] = v.w;
  }
  __syncthreads();
#pragma unroll
  for (int i = 0; i < 4; i++) {
    int n = r + i * 16;
    s16x4 o;
#pragma unroll
    for (int j = 0; j < 4; j++) o[j] = (short)f2bf(tile[c4 + j][n]);
    *(s16x4*)(Wt + (size_t)(n0 + n) * Ff + k0 + c4) = o;
  }
}

// ---------------- mask tile summary: flag=1 iff whole 64x64 tile > 0 ----------------
__global__ __launch_bounds__(256) void maskflag_kernel(const int* __restrict__ mask, int* __restrict__ flags) {
  int kb = blockIdx.x, qb = blockIdx.y, b = blockIdx.z;
  int t = threadIdx.x;
  __shared__ int s;
  if (t == 0) s = 1;
  __syncthreads();
  int ok = 1;
#pragma unroll
  for (int i = 0; i < 4; i++) {
    int row = qb * 64 + (t >> 4) + i * 16;
    const int4 v = *(const int4*)(mask + ((size_t)b * Tt + row) * Tt + kb * 64 + (t & 15) * 4);
    ok &= (v.x > 0) & (v.y > 0) & (v.z > 0) & (v.w > 0);
  }
  atomicAnd(&s, ok);
  __syncthreads();
  if (t == 0) flags[(b * 32 + qb) * 32 + kb] = s;
}

// ---------------- bf16 GEMM, C = A[M,K] * Bt[N,K]^T (+bias)*scale ----------------
// T4 counted-vmcnt ring-3 pipeline, BK=32 (48 KB LDS -> 3 blocks/CU; grid 768 = exactly 3/CU).
// Loop: wait vmcnt(4) [tile t landed, t+1 in flight] -> raw s_barrier -> stage(t+2) -> compute(t).
// Loads are NEVER drained to 0 in the main loop (round-4 lesson: drain0 barrier = the stall).
// 64B LDS rows make b128 fragment reads bank-balanced without swizzle (8 words/bank/wave-read).
// mode 0: f32 row-major out. mode 1: bf16 row-major out. mode 2: bf16 V-fragment layout
//   (Vpt[(b*Ff+n)][kv], columns pi-permuted per 64-block: kv=32c+16f+4g+r stored at p=32c+8g+4f+r).
DI void gemm_core(const ushort* __restrict__ A, const ushort* __restrict__ Bt,
                  const float* __restrict__ bias, void* __restrict__ Cout, float scale, int mode,
                  int m0, int n0) {
  __shared__ ushort Ads[3][128 * 32];  // 24 KB ring
  __shared__ ushort Bds[3][128 * 32];  // 24 KB ring
  const int tid = threadIdx.x, lane = tid & 63, w = tid >> 6;
  const int wr = w >> 1, wc = w & 1;
  const int g = lane >> 4, ln = lane & 15;
  const int strow = tid >> 2;      // staging row 0..63 (per it-pass)
  const int stc = (tid & 3) * 8;   // staging 16B-chunk offset (ushorts)

  // per-thread staging bases (linear layout, no swizzle needed at BK=32)
  const ushort* Asrc0 = A + (size_t)(m0 + strow) * Ff + stc;
  const ushort* Asrc1 = A + (size_t)(m0 + 64 + strow) * Ff + stc;
  const ushort* Bsrc0 = Bt + (size_t)(n0 + strow) * Ff + stc;
  const ushort* Bsrc1 = Bt + (size_t)(n0 + 64 + strow) * Ff + stc;
  const int dst0 = strow * 32 + stc;          // = wave-uniform + lane*8 ushorts
  const int dst1 = (64 + strow) * 32 + stc;

  f32x4 acc[4][4];
#pragma unroll
  for (int m = 0; m < 4; m++)
#pragma unroll
    for (int n = 0; n < 4; n++) acc[m][n] = (f32x4){0.f, 0.f, 0.f, 0.f};

  auto stage = [&](int t, int slot) {
    const int k0 = t * 32;
    gload16(Asrc0 + k0, Ads[slot] + dst0);
    gload16(Asrc1 + k0, Ads[slot] + dst1);
    gload16(Bsrc0 + k0, Bds[slot] + dst0);
    gload16(Bsrc1 + k0, Bds[slot] + dst1);
  };

  // prologue: stage tiles 0,1 (8 loads outstanding)
  stage(0, 0);
  stage(1, 1);

  int rs = 0, ws = 2;
  for (int t = 0; t < 32; ++t) {
    if (t < 31) wait_vm4(); else wait_vm0();   // tile t resident; tile t+1 stays in flight
    __builtin_amdgcn_s_barrier();
    __builtin_amdgcn_sched_barrier(0);
    if (t < 30) stage(t + 2, ws);              // issue-early: 2 compute phases of latency cover
    const ushort* As = Ads[rs];
    const ushort* Bs = Bds[rs];
    s16x8 af[4], bf[4];
#pragma unroll
    for (int m = 0; m < 4; m++) af[m] = *(const s16x8*)(As + (wr * 64 + m * 16 + ln) * 32 + g * 8);
#pragma unroll
    for (int n = 0; n < 4; n++) bf[n] = *(const s16x8*)(Bs + (wc * 64 + n * 16 + ln) * 32 + g * 8);
    __builtin_amdgcn_s_setprio(1);
#pragma unroll
    for (int m = 0; m < 4; m++)
#pragma unroll
      for (int n = 0; n < 4; n++)
        acc[m][n] = __builtin_amdgcn_mfma_f32_16x16x32_bf16(af[m], bf[n], acc[m][n], 0, 0, 0);
    __builtin_amdgcn_s_setprio(0);
    rs = rs == 2 ? 0 : rs + 1;
    ws = ws == 2 ? 0 : ws + 1;
  }
#pragma unroll
  for (int m = 0; m < 4; m++) {
    const int r0 = m0 + wr * 64 + m * 16 + g * 4;
#pragma unroll
    for (int n = 0; n < 4; n++) {
      const int col = n0 + wc * 64 + n * 16 + ln;
      const float bv = bias[col];
      if (mode == 2) {
        // V-fragment store: batch bb, row-in-batch rb, pi^-1 on kv within 64-block
        const int bb = r0 >> 11, rb = r0 & 2047;
        const int x = rb & 63;
        const int pbase = (x & 0x20) | ((x & 0x0C) << 1) | ((x & 0x10) >> 2);
        s16x4 o4;
#pragma unroll
        for (int r = 0; r < 4; r++) o4[r] = (short)f2bf(acc[m][n][r] + bv);
        *(s16x4*)((ushort*)Cout + ((size_t)bb * Ff + col) * Tt + (rb & ~63) + pbase) = o4;
      } else {
#pragma unroll
        for (int r = 0; r < 4; r++) {
          const float val = (acc[m][n][r] + bv) * scale;
          if (mode == 1)
            ((ushort*)Cout)[(size_t)(r0 + r) * Ff + col] = f2bf(val);
          else
            ((float*)Cout)[(size_t)(r0 + r) * Ff + col] = val;
        }
      }
    }
  }
}

__global__ __launch_bounds__(256) void qkv_gemm_kernel(
    const ushort* __restrict__ Xq, const ushort* __restrict__ Xk, const ushort* __restrict__ Xv,
    const ushort* __restrict__ Wqt, const ushort* __restrict__ Wkt, const ushort* __restrict__ Wvt,
    const float* __restrict__ bq, const float* __restrict__ bk, const float* __restrict__ bv,
    ushort* __restrict__ Qb, ushort* __restrict__ Kb, ushort* __restrict__ Vpt) {
  // T1: XCD-chunked bijective block swizzle (768 blocks -> 96 contiguous per XCD)
  const int lin = blockIdx.x + 8 * blockIdx.y + 256 * blockIdx.z;
  const int work = (lin & 7) * 96 + (lin >> 3);
  const int z = work >> 8;
  const int r = work & 255;
  const int m0 = (r >> 3) * 128, n0 = (r & 7) * 128;
  const ushort* A = z == 0 ? Xq : (z == 1 ? Xk : Xv);
  const ushort* Wt = z == 0 ? Wqt : (z == 1 ? Wkt : Wvt);
  const float* bias = z == 0 ? bq : (z == 1 ? bk : bv);
  void* C = z == 0 ? (void*)Qb : (z == 1 ? (void*)Kb : (void*)Vpt);
  // z==0: fold 1/sqrt(64) AND log2(e) into Q so softmax runs in exp2 domain
  const float scale = z == 0 ? 0.125f * LOG2E : 1.0f;
  gemm_core(A, Wt, bias, C, scale, z == 2 ? 2 : 1, m0, n0);
}

__global__ __launch_bounds__(256) void out_gemm_kernel(const ushort* __restrict__ AO,
                                                       const ushort* __restrict__ Wot,
                                                       const float* __restrict__ bo,
                                                       float* __restrict__ Out) {
  // T1: XCD-chunked bijective block swizzle (256 blocks -> 32 contiguous per XCD)
  const int lin = blockIdx.x + 8 * blockIdx.y;
  const int work = (lin & 7) * 32 + (lin >> 3);
  const int m0 = (work >> 3) * 128, n0 = (work & 7) * 128;
  gemm_core(AO, Wot, bo, Out, 1.0f, 0, m0, n0);
}

// ---------------- flash attention (max-free exp2 softmax, QBLK=128, T4 ring-3) ----------------
// grid (qb=16, h=16, b=2), 256 thr (4 waves). BQ=128 (two 16-row groups/wave), BK=64, D=64.
// K/V staged in a ring of 3 (48 KB); loop = wait vmcnt(4) -> raw s_barrier -> stage(kt+2) ->
// compute(kt). No __syncthreads: prefetch loads never drain to 0 in the loop.
// S'^T = mfma(K_frag, Q_frag), scores in log2 domain (Q pre-scaled by 0.125*log2e);
// raw exp2, lane-local l, cross-lane reduce deferred to epilogue.
// lane (g,ln): group j covers q = qb*128 + j*64 + w*16 + ln; kv(sf[ks][r]) = kt*64+16ks+4g+r.
// PV sigma k-slots on BOTH operands: slot (c,g,i=4f+r) <-> kv = 32c+16f+4g+r;
//   A-op packed in-register via v_cvt_pk; B-op = single b128 from pi-ordered d-major V LDS.
__global__ __launch_bounds__(256) void flash_kernel(
    const ushort* __restrict__ Qb, const ushort* __restrict__ Kb, const ushort* __restrict__ Vpt,
    const int* __restrict__ flags, const int* __restrict__ mask, ushort* __restrict__ AO) {
  __shared__ ushort Ks[3][64 * 64];
  __shared__ ushort Vs[3][64 * 64];
  // T1: XCD-chunked bijective block swizzle (512 blocks -> 64 per XCD = 4 heads' KV, L2-fit)
  const int lin = blockIdx.x + 16 * (blockIdx.y + 16 * blockIdx.z);
  const int work = (lin & 7) * 64 + (lin >> 3);
  const int qb = work & 15, h = (work >> 4) & 15, b = work >> 8;
  const int tid = threadIdx.x, lane = tid & 63, w = tid >> 6;
  const int g = lane >> 4, ln = lane & 15;

  const ushort* Qg = Qb + ((size_t)b * Tt + qb * 128) * Ff + h * Dk;
  const ushort* Kg = Kb + ((size_t)b * Tt) * Ff + h * Dk;
  const ushort* Vg = Vpt + (size_t)(b * Ff + h * Dk) * Tt;  // rows d, stride Tt, cols pi-ordered

  const int srow = lane >> 3;
  const int swzch = ((lane & 7) ^ srow) * 8;  // inverse-swizzled source chunk (128B rows need XOR)

  // Q fragments + mask flags issued FIRST (oldest in vmcnt queue, done by first wait)
  s16x8 qf0[2], qf1[2];
  {
    const ushort* Qrow0 = Qg + (size_t)(w * 16 + ln) * Ff;
    const ushort* Qrow1 = Qrow0 + (size_t)64 * Ff;
    qf0[0] = *(const s16x8*)(Qrow0 + g * 8);
    qf0[1] = *(const s16x8*)(Qrow0 + 32 + g * 8);
    qf1[0] = *(const s16x8*)(Qrow1 + g * 8);
    qf1[1] = *(const s16x8*)(Qrow1 + 32 + g * 8);
  }
  const int* flagrow0 = flags + (b * 32 + qb * 2) * 32;
  const int f0 = (lane < 32) ? flagrow0[lane] : 1;
  const int f1 = (lane < 32) ? flagrow0[32 + lane] : 1;

  auto stage = [&](int t, int slot) {
    const ushort* Kg2 = Kg + (size_t)t * 64 * Ff;
    const ushort* Vg2 = Vg + (size_t)t * 64;
#pragma unroll
    for (int it = 0; it < 2; ++it) {
      const int row = w * 16 + it * 8;
      gload16(Kg2 + (size_t)(row + srow) * Ff + swzch, Ks[slot] + row * 64);
      gload16(Vg2 + (size_t)(row + srow) * Tt + swzch, Vs[slot] + row * 64);
    }
  };
  stage(0, 0);
  stage(1, 1);
  const unsigned long long bm0 = __ballot(f0 == 0);
  const unsigned long long bm1 = __ballot(f1 == 0);

  float l0 = 0.f, l1 = 0.f;  // lane-local partial denominators (per q-group)
  f32x4 o0[4], o1[4];
#pragma unroll
  for (int ds = 0; ds < 4; ds++) { o0[ds] = (f32x4){0.f, 0.f, 0.f, 0.f}; o1[ds] = (f32x4){0.f, 0.f, 0.f, 0.f}; }

  int rs = 0, ws = 2;
  for (int kt = 0; kt < 32; ++kt) {
    if (kt < 31) wait_vm4(); else wait_vm0();  // tile kt resident; kt+1 stays in flight
    __builtin_amdgcn_s_barrier();
    __builtin_amdgcn_sched_barrier(0);
    if (kt < 30) stage(kt + 2, ws);
    const ushort* Kc = Ks[rs];
    const ushort* Vc = Vs[rs];
    // --- S'^T = K * Q^T (log2 domain); each kf feeds BOTH q-groups ---
    f32x4 sf0[4], sf1[4];
    __builtin_amdgcn_s_setprio(1);
#pragma unroll
    for (int ks = 0; ks < 4; ++ks) {
      f32x4 a0 = (f32x4){0.f, 0.f, 0.f, 0.f};
      f32x4 a1 = (f32x4){0.f, 0.f, 0.f, 0.f};
#pragma unroll
      for (int c = 0; c < 2; c++) {
        const int row = ks * 16 + ln;
        const int off = (c * 64 + g * 16) ^ ((row & 7) << 4);
        const s16x8 kf = *(const s16x8*)((const char*)Kc + row * 128 + off);
        a0 = __builtin_amdgcn_mfma_f32_16x16x32_bf16(kf, qf0[c], a0, 0, 0, 0);
        a1 = __builtin_amdgcn_mfma_f32_16x16x32_bf16(kf, qf1[c], a1, 0, 0, 0);
      }
      sf0[ks] = a0; sf1[ks] = a1;
    }
    __builtin_amdgcn_s_setprio(0);
    // --- mask (skipped for all-positive tiles); masked scores -> -10000 -> exp2 -> 0 ---
    if ((bm0 >> kt) & 1ull) {
      const int qg_ = qb * 128 + w * 16 + ln;
#pragma unroll
      for (int ks = 0; ks < 4; ++ks) {
        const int4 mv = *(const int4*)(mask + ((size_t)b * Tt + qg_) * Tt + kt * 64 + ks * 16 + g * 4);
        if (mv.x <= 0) sf0[ks][0] = -10000.f;
        if (mv.y <= 0) sf0[ks][1] = -10000.f;
        if (mv.z <= 0) sf0[ks][2] = -10000.f;
        if (mv.w <= 0) sf0[ks][3] = -10000.f;
      }
    }
    if ((bm1 >> kt) & 1ull) {
      const int qg_ = qb * 128 + 64 + w * 16 + ln;
#pragma unroll
      for (int ks = 0; ks < 4; ++ks) {
        const int4 mv = *(const int4*)(mask + ((size_t)b * Tt + qg_) * Tt + kt * 64 + ks * 16 + g * 4);
        if (mv.x <= 0) sf1[ks][0] = -10000.f;
        if (mv.y <= 0) sf1[ks][1] = -10000.f;
        if (mv.z <= 0) sf1[ks][2] = -10000.f;
        if (mv.w <= 0) sf1[ks][3] = -10000.f;
      }
    }
    // --- raw exp2 (no max subtraction) + lane-local denominator partials ---
    float a0 = 0.f, a1 = 0.f;
#pragma unroll
    for (int ks = 0; ks < 4; ++ks) {
#pragma unroll
      for (int r = 0; r < 4; ++r) {
        const float p0 = __builtin_amdgcn_exp2f(sf0[ks][r]);
        const float p1 = __builtin_amdgcn_exp2f(sf1[ks][r]);
        sf0[ks][r] = p0; sf1[ks][r] = p1;
        a0 += p0; a1 += p1;
      }
    }
    l0 += a0; l1 += a1;
    // --- pack P A-frags via v_cvt_pk: word w of pa{j}[c] = slots (2w,2w+1), i=4f+r ---
    i32x4 paw0[2], paw1[2];
#pragma unroll
    for (int c = 0; c < 2; c++)
#pragma unroll
      for (int f = 0; f < 2; f++)
#pragma unroll
        for (int hh = 0; hh < 2; hh++) {
          paw0[c][f * 2 + hh] = cvt_pk_bf16(sf0[2 * c + f][2 * hh], sf0[2 * c + f][2 * hh + 1]);
          paw1[c][f * 2 + hh] = cvt_pk_bf16(sf1[2 * c + f][2 * hh], sf1[2 * c + f][2 * hh + 1]);
        }
    const s16x8 pa00 = __builtin_bit_cast(s16x8, paw0[0]);
    const s16x8 pa01 = __builtin_bit_cast(s16x8, paw0[1]);
    const s16x8 pa10 = __builtin_bit_cast(s16x8, paw1[0]);
    const s16x8 pa11 = __builtin_bit_cast(s16x8, paw1[1]);
    // --- PV: single b128 B-frags from pi-ordered V LDS; each vf feeds BOTH q-groups ---
    __builtin_amdgcn_s_setprio(1);
#pragma unroll
    for (int ds = 0; ds < 4; ++ds) {
      const int row = ds * 16 + ln;
#pragma unroll
      for (int c = 0; c < 2; ++c) {
        const int off = (c * 64 + g * 16) ^ ((row & 7) << 4);
        const s16x8 vf = *(const s16x8*)((const char*)Vc + row * 128 + off);
        o0[ds] = __builtin_amdgcn_mfma_f32_16x16x32_bf16(c == 0 ? pa00 : pa01, vf, o0[ds], 0, 0, 0);
        o1[ds] = __builtin_amdgcn_mfma_f32_16x16x32_bf16(c == 0 ? pa10 : pa11, vf, o1[ds], 0, 0, 0);
      }
    }
    __builtin_amdgcn_s_setprio(0);
    rs = rs == 2 ? 0 : rs + 1;
    ws = ws == 2 ? 0 : ws + 1;
  }

  // --- epilogue: deferred cross-lane l reduction, normalize, store bf16 ---
  // o{j} reg r is q_local=4g+r, col=ds*16+ln; l lives at lane ln'=q_local (after g-reduce)
  l0 += __shfl_xor(l0, 16); l0 += __shfl_xor(l0, 32);
  l1 += __shfl_xor(l1, 16); l1 += __shfl_xor(l1, 32);
  float inv0[4], inv1[4];
#pragma unroll
  for (int r = 0; r < 4; ++r) {
    inv0[r] = 1.0f / __shfl(l0, g * 4 + r);
    inv1[r] = 1.0f / __shfl(l1, g * 4 + r);
  }
  ushort* AOg0 = AO + ((size_t)b * Tt + qb * 128 + w * 16) * Ff + h * Dk;
  ushort* AOg1 = AOg0 + (size_t)64 * Ff;
#pragma unroll
  for (int ds = 0; ds < 4; ++ds)
#pragma unroll
    for (int r = 0; r < 4; ++r) {
      AOg0[(size_t)(g * 4 + r) * Ff + ds * 16 + ln] = f2bf(o0[ds][r] * inv0[r]);
      AOg1[(size_t)(g * 4 + r) * Ff + ds * 16 + ln] = f2bf(o1[ds][r] * inv1[r]);
    }
}

// ---------------- host launch ----------------
extern "C" void kernel_launch(void* const* d_in, const int* in_sizes, int n_in,
                              void* d_out, int out_size, void* d_ws, size_t ws_size,
                              hipStream_t stream) {
  const float* query = (const float*)d_in[0];
  const float* key_  = (const float*)d_in[1];
  const float* value = (const float*)d_in[2];
  const int*   mask  = (const int*)d_in[3];
  const float* Wq = (const float*)d_in[4];  const float* bq = (const float*)d_in[5];
  const float* Wk = (const float*)d_in[6];  const float* bk = (const float*)d_in[7];
  const float* Wv = (const float*)d_in[8];  const float* bv = (const float*)d_in[9];
  const float* Wo = (const float*)d_in[10]; const float* bo = (const float*)d_in[11];
  float* Out = (float*)d_out;

  constexpr size_t SZ_X = (size_t)Mm * Ff * 2;  // 8 MB bf16 matrix
  constexpr size_t SZ_W = (size_t)Ff * Ff * 2;  // 2 MB bf16 weight
  uintptr_t p = (uintptr_t)d_ws;
  auto alloc = [&](size_t sz) { void* r = (void*)p; p += (sz + 255) & ~(size_t)255; return r; };
  ushort* Xq = (ushort*)alloc(SZ_X);
  ushort* Xk = (ushort*)alloc(SZ_X);
  ushort* Xv = (ushort*)alloc(SZ_X);
  ushort* Wqt = (ushort*)alloc(SZ_W);
  ushort* Wkt = (ushort*)alloc(SZ_W);
  ushort* Wvt = (ushort*)alloc(SZ_W);
  ushort* Wot = (ushort*)alloc(SZ_W);
  ushort* Qp  = (ushort*)alloc(SZ_X);
  ushort* Kp  = (ushort*)alloc(SZ_X);
  ushort* Vpt = (ushort*)alloc(SZ_X);  // [b][d][kv], pi-ordered columns, written by qkv_gemm z=2
  int* flags = (int*)alloc((size_t)Bb * 32 * 32 * 4);
  ushort* AO = Xq;  // alias: flash output (Xq dead after qkv_gemm)

  const int n8 = Mm * Ff / 8;  // 524288
  cvt3_kernel<<<dim3(2048, 3), 256, 0, stream>>>(query, key_, value, Xq, Xk, Xv, n8);
  wtrans_kernel<<<dim3(16, 16, 4), 256, 0, stream>>>(Wq, Wk, Wv, Wo, Wqt, Wkt, Wvt, Wot);
  maskflag_kernel<<<dim3(32, 32, 2), 256, 0, stream>>>(mask, flags);
  qkv_gemm_kernel<<<dim3(8, 32, 3), 256, 0, stream>>>(Xq, Xk, Xv, Wqt, Wkt, Wvt, bq, bk, bv, Qp, Kp, Vpt);
  flash_kernel<<<dim3(16, 16, 2), 256, 0, stream>>>(Qp, Kp, Vpt, flags, mask, AO);
  out_gemm_kernel<<<dim3(8, 32), 256, 0, stream>>>(AO, Wot, bo, Out);
}